// Round 7
// baseline (400.687 us; speedup 1.0000x reference)
//
#include <hip/hip_runtime.h>

typedef unsigned short u16;
typedef unsigned int   u32;
typedef __bf16 bf16x8 __attribute__((ext_vector_type(8)));
typedef float  f32x4  __attribute__((ext_vector_type(4)));

#define EPS 1e-5f
#define BSHIFT 9               // 512 node ids per bucket

__device__ __forceinline__ float b2f(u16 u){ union{u32 i; float f;} v; v.i=((u32)u)<<16; return v.f; }
__device__ __forceinline__ u16 f2b(float f){
  u32 x = __float_as_uint(f);
  u32 r = x + 0x7fffu + ((x>>16)&1u);   // round-to-nearest-even
  return (u16)(r>>16);
}

// ---- GEMM: C[M,128] = act(A[M,K] @ (Bhi+Blo) + bias), fused per-feature BN stats ----
// v6 (resubmit; round-6 bench was an infra failure, not a kernel fault):
// col-split 64-col blocks + XCD-paired halves (b, b+grid/2: 512%8==0 -> same XCD,
// share A via L2). RT=2 inline static (v5). POOL epilogue rebuilt to cut global
// atomics ~4-8x (v5 counters: all pipes idle at 50us; 1.6M atomicAdds ~= the floor):
//   - one graph-loop per macro-tile folding both row-slices (2x fewer flushes+shfls)
//   - lane l holds col-l sum (select nb==q after q-fold) -> 64-lane 1-op flush
//   - contiguous tile ranges (bijective split) + per-wave running (gc, rs) accum:
//     flush only on graph transition (~4/block-wave instead of 8/tile)
// NO min-waves launch bound (r2/r4: forced bounds -> scratch spill).
template<int K, bool RELU, bool HASBIAS, bool AF32, bool POOL>
__global__ __launch_bounds__(256) void k_gemm(const void* __restrict__ Av,
                                              const u16* __restrict__ BhiT,
                                              const u16* __restrict__ BloT,
                                              const float* __restrict__ bias,
                                              u16* __restrict__ C,
                                              float* __restrict__ stats,
                                              const int* __restrict__ batch,
                                              float* __restrict__ P, int M)
{
  constexpr int KM = K / 8;                 // 8-elem (16B) blocks per row
  constexpr int KR = K / 32;                // bf16x8 fragments per lane
  __shared__ u16 lds[2 * 64 * K];           // [hi|lo][64 cols][K swizzled]
  __shared__ float sred[64], qred[64];
  const int tid = threadIdx.x;
  const int halfg = gridDim.x >> 1;
  const int ch = (blockIdx.x >= halfg) ? 1 : 0;   // column half: cols ch*64..+63
  const int t0 = blockIdx.x - ch * halfg;         // pair (b, b+halfg): same XCD
  for (int i = tid; i < 64 * KM; i += 256) {
    const int n = i / KM, kb = i % KM;
    const int kb2 = kb ^ (n & (KM - 1));
    const int gsrc = ((ch * 64 + n) * KM + kb) * 8;
    *(uint4*)(&lds[(n * KM + kb2) * 8])          = *(const uint4*)(BhiT + gsrc);
    *(uint4*)(&lds[64 * K + (n * KM + kb2) * 8]) = *(const uint4*)(BloT + gsrc);
  }
  if (tid < 64) { sred[tid] = 0.f; qred[tid] = 0.f; }
  __syncthreads();
  const int wid = tid >> 6, lane = tid & 63, q = lane >> 4, r16 = lane & 15;
  const int nmt = (M + 127) >> 7;           // 128-row macro tiles (M % 64 == 0)
  // bijective contiguous tile range for this block
  const int qt = nmt / halfg, rm = nmt % halfg;
  const int tstart = (t0 < rm) ? t0 * (qt + 1) : rm * (qt + 1) + (t0 - rm) * qt;
  const int tend   = tstart + ((t0 < rm) ? qt + 1 : qt);
  float ls[4], lq[4];
#pragma unroll
  for (int nb = 0; nb < 4; nb++) { ls[nb] = 0.f; lq[nb] = 0.f; }
  float bv[4];
#pragma unroll
  for (int nb = 0; nb < 4; nb++) bv[nb] = HASBIAS ? bias[ch * 64 + nb * 16 + r16] : 0.f;

  int gc = -1;            // current graph (wave-uniform), POOL only
  float rs = 0.f;         // running col-sum for gc (lane l = col ch*64+l)

  for (int mt = tstart; mt < tend; mt++) {
    const int row0 = mt << 7;               // rt=0 rows always valid
    const bool ok1 = (row0 + 64) < M;       // rt=1 rows row0+64..127

    bf16x8 av[2][KR];
    if (AF32) {
      const float* Af = (const float*)Av + (size_t)(row0 + (wid << 4) + r16) * K + q * 8;
#pragma unroll
      for (int kk = 0; kk < KR; kk++) {
        f32x4 x0 = *(const f32x4*)(Af + kk * 32);
        f32x4 x1 = *(const f32x4*)(Af + kk * 32 + 4);
#pragma unroll
        for (int j = 0; j < 4; j++) { av[0][kk][j] = (__bf16)x0[j]; av[0][kk][4 + j] = (__bf16)x1[j]; }
      }
      if (ok1) {
        const float* Ag = Af + (size_t)64 * K;
#pragma unroll
        for (int kk = 0; kk < KR; kk++) {
          f32x4 x0 = *(const f32x4*)(Ag + kk * 32);
          f32x4 x1 = *(const f32x4*)(Ag + kk * 32 + 4);
#pragma unroll
          for (int j = 0; j < 4; j++) { av[1][kk][j] = (__bf16)x0[j]; av[1][kk][4 + j] = (__bf16)x1[j]; }
        }
      }
    } else {
      const u16* Ab = (const u16*)Av + (size_t)(row0 + (wid << 4) + r16) * K + q * 8;
#pragma unroll
      for (int kk = 0; kk < KR; kk++) av[0][kk] = *(const bf16x8*)(Ab + kk * 32);
      if (ok1) {
#pragma unroll
        for (int kk = 0; kk < KR; kk++) av[1][kk] = *(const bf16x8*)(Ab + (size_t)64 * K + kk * 32);
      }
    }

    f32x4 acc[2][4];
#pragma unroll
    for (int rt = 0; rt < 2; rt++)
#pragma unroll
      for (int nb = 0; nb < 4; nb++) acc[rt][nb] = (f32x4){0.f, 0.f, 0.f, 0.f};
#pragma unroll
    for (int kk = 0; kk < KR; kk++) {
#pragma unroll
      for (int nb = 0; nb < 4; nb++) {
        const int n = nb * 16 + r16;
        const int kb2 = (kk * 4 + q) ^ (n & (KM - 1));
        const bf16x8 bh = *(const bf16x8*)(&lds[(n * KM + kb2) * 8]);
        const bf16x8 bl = *(const bf16x8*)(&lds[64 * K + (n * KM + kb2) * 8]);
        acc[0][nb] = __builtin_amdgcn_mfma_f32_16x16x32_bf16(av[0][kk], bh, acc[0][nb], 0, 0, 0);
        acc[0][nb] = __builtin_amdgcn_mfma_f32_16x16x32_bf16(av[0][kk], bl, acc[0][nb], 0, 0, 0);
        if (ok1) {
          acc[1][nb] = __builtin_amdgcn_mfma_f32_16x16x32_bf16(av[1][kk], bh, acc[1][nb], 0, 0, 0);
          acc[1][nb] = __builtin_amdgcn_mfma_f32_16x16x32_bf16(av[1][kk], bl, acc[1][nb], 0, 0, 0);
        }
      }
    }

    // bias + relu + BN stats (both row-slices); POOL keeps activated f32 in acc
#pragma unroll
    for (int rt = 0; rt < 2; rt++) {
      if (rt && !ok1) continue;
      const int rbase = row0 + rt * 64 + (wid << 4) + (q << 2);
#pragma unroll
      for (int nb = 0; nb < 4; nb++) {
        const int col = ch * 64 + nb * 16 + r16;
#pragma unroll
        for (int r = 0; r < 4; r++) {
          float v = acc[rt][nb][r] + bv[nb];
          if (RELU) v = fmaxf(v, 0.f);
          ls[nb] += v; lq[nb] += v * v;
          if (!POOL) C[(size_t)(rbase + r) * 128 + col] = f2b(v);
          else acc[rt][nb][r] = v;
        }
      }
    }

    if (POOL) {
      // merged graph loop over both row-slices
      int bg0[4], bg1[4];
      const int rb0 = row0 + (wid << 4) + (q << 2);
#pragma unroll
      for (int r = 0; r < 4; r++) bg0[r] = batch[rb0 + r];
      if (ok1) {
#pragma unroll
        for (int r = 0; r < 4; r++) bg1[r] = batch[rb0 + 64 + r];
      } else {
#pragma unroll
        for (int r = 0; r < 4; r++) bg1[r] = bg0[r];
      }
      const int gA = __shfl(bg0[0], 0, 64);                 // first row of wave slice
      const int gB = ok1 ? __shfl(bg1[3], 48, 64) : __shfl(bg0[3], 48, 64);  // last row
      for (int g = gA; g <= gB; ++g) {                      // wave-uniform, ~1-2 iters
        float cs = 0.f;
#pragma unroll
        for (int nb = 0; nb < 4; nb++) {
          float sv = 0.f;
#pragma unroll
          for (int r = 0; r < 4; r++) sv += (bg0[r] == g) ? acc[0][nb][r] : 0.f;
          if (ok1) {
#pragma unroll
            for (int r = 0; r < 4; r++) sv += (bg1[r] == g) ? acc[1][nb][r] : 0.f;
          }
          sv += __shfl_xor(sv, 16, 64);                     // fold the 4 q-groups
          sv += __shfl_xor(sv, 32, 64);
          cs = (q == nb) ? sv : cs;                         // lane l keeps col l
        }
        if (g == gc) {
          rs += cs;
        } else {
          if (gc >= 0) atomicAdd(&P[gc * 128 + ch * 64 + lane], rs);
          gc = g; rs = cs;
        }
      }
    }
  }
  if (POOL && gc >= 0) atomicAdd(&P[gc * 128 + ch * 64 + lane], rs);
#pragma unroll
  for (int nb = 0; nb < 4; nb++) {
    atomicAdd(&sred[nb * 16 + r16], ls[nb]);
    atomicAdd(&qred[nb * 16 + r16], lq[nb]);
  }
  __syncthreads();
  if (tid < 64) {
    atomicAdd(&stats[ch * 64 + tid], sred[tid]);
    atomicAdd(&stats[128 + ch * 64 + tid], qred[tid]);
  }
}

// ---- prep0: blocks [0,NZ) zero scratch; [NZ,NZ+48) split Wg/W2 hi/lo T; rest: bounds ----
__global__ void k_prep0(const float* __restrict__ Wg, const float* __restrict__ W2,
                        u16* __restrict__ WghiT, u16* __restrict__ WgloT,
                        u16* __restrict__ W2hiT, u16* __restrict__ W2loT,
                        const int* __restrict__ batch, int* __restrict__ gofs,
                        int* __restrict__ zbase, int zwords, int NZ, int N, int B)
{
  const int bid = blockIdx.x, t = threadIdx.x;
  if (bid < NZ) {
    const int i = bid * 2048 + t * 8;       // zwords padded to multiple of 8
    if (i < zwords) {
      *(int4*)(zbase + i)     = make_int4(0, 0, 0, 0);
      *(int4*)(zbase + i + 4) = make_int4(0, 0, 0, 0);
    }
  } else if (bid < NZ + 48) {
    const int i = (bid - NZ) * 256 + t;
    if (i < 64 * 128) {
      int k = i >> 7, n = i & 127;
      float w = Wg[i]; u16 h = f2b(w);
      WghiT[n * 64 + k] = h; WgloT[n * 64 + k] = f2b(w - b2f(h));
    } else if (i < 64 * 128 + 32 * 128) {
      int j = i - 64 * 128;
      int k = j >> 7, n = j & 127;
      float w = W2[j]; u16 h = f2b(w);
      W2hiT[n * 32 + k] = h; W2loT[n * 32 + k] = f2b(w - b2f(h));
    }
  } else {
    const int i = (bid - NZ - 48) * 256 + t;
    if (i == 0) { for (int g = 0; g <= batch[0]; g++) gofs[g] = 0; }
    if (i == N - 1) { for (int g = batch[N - 1] + 1; g <= B; g++) gofs[g] = N; }
    if (i < N - 1) {
      const int b0 = batch[i], b1 = batch[i + 1];
      for (int g = b0 + 1; g <= b1; g++) gofs[g] = i + 1;
    }
  }
}

// ========== binned edge partition ==========
__global__ __launch_bounds__(256) void k_bincnt(const int* __restrict__ dst, int* __restrict__ btot,
                                                int E, int NB)
{
  extern __shared__ int hist[];
  const int tid = threadIdx.x;
  for (int i = tid; i < NB; i += 256) hist[i] = 0;
  __syncthreads();
  const int chunk = (E + gridDim.x - 1) / gridDim.x;
  const int start = blockIdx.x * chunk;
  const int end = min(start + chunk, E);
  for (int e = start + tid; e < end; e += 256) atomicAdd(&hist[((u32)dst[e]) >> BSHIFT], 1);
  __syncthreads();
  for (int i = tid; i < NB; i += 256) if (hist[i]) atomicAdd(&btot[i], hist[i]);
}

// single-block exclusive scan; out[0..n-1] = exclusive, out[n] = total
__global__ void k_exscan(const int* __restrict__ in, int* __restrict__ out, int n)
{
  __shared__ int s[256];
  const int t = threadIdx.x;
  const int per = (n + 255) / 256;
  const int base = t * per;
  int loc[8]; int sum = 0;
  for (int j = 0; j < per; j++) { int v = (base + j < n) ? in[base + j] : 0; loc[j] = sum; sum += v; }
  s[t] = sum; __syncthreads();
  for (int o = 1; o < 256; o <<= 1) {
    int x = (t >= o) ? s[t - o] : 0;
    __syncthreads();
    s[t] += x;
    __syncthreads();
  }
  const int ex = s[t] - sum;
  for (int j = 0; j < per; j++) if (base + j < n) out[base + j] = ex + loc[j];
  if (t == 255) out[n] = s[255];
}

// re-read edges, reserve per-(block,bucket) ranges, stream (dst,src) pairs
__global__ __launch_bounds__(256) void k_bin(const int* __restrict__ src, const int* __restrict__ dst,
                                             const int* __restrict__ bbase, int* __restrict__ bcur,
                                             uint2* __restrict__ pairs, int E, int NB)
{
  extern __shared__ int lds[];
  int* hist = lds; int* wbase = lds + NB;
  const int tid = threadIdx.x;
  for (int i = tid; i < NB; i += 256) hist[i] = 0;
  __syncthreads();
  const int chunk = (E + gridDim.x - 1) / gridDim.x;
  const int start = blockIdx.x * chunk;
  const int end = min(start + chunk, E);
  for (int e = start + tid; e < end; e += 256) atomicAdd(&hist[((u32)dst[e]) >> BSHIFT], 1);
  __syncthreads();
  for (int i = tid; i < NB; i += 256) {
    int c = hist[i];
    wbase[i] = c ? bbase[i] + atomicAdd(&bcur[i], c) : 0;
    hist[i] = 0;
  }
  __syncthreads();
  for (int e = start + tid; e < end; e += 256) {
    const int d = dst[e];
    const int b = ((u32)d) >> BSHIFT;
    const int o = atomicAdd(&hist[b], 1);
    pairs[wbase[b] + o] = make_uint2((u32)d, (u32)src[e]);
  }
}

// ---- per-bucket: degree hist -> LDS scan -> offsets/dinv/self-loop -> scatter ----
// Also fused: y[i] = bf16(x[i] * dinv[i]) for the bucket's own 512 nodes (coalesced).
__global__ __launch_bounds__(256) void k_bucket(const uint2* __restrict__ pairs,
                                                const int* __restrict__ bbase,
                                                const float* __restrict__ x,
                                                int* __restrict__ offsets, float* __restrict__ dinv,
                                                int* __restrict__ elist, u16* __restrict__ y,
                                                int N, int NB, int Etot)
{
  __shared__ int hist[512];
  __shared__ int scan[256];
  __shared__ int lcur[512];
  __shared__ float sdinv[512];
  const int b = blockIdx.x, t = threadIdx.x;
  const int nbase = b << BSHIFT;
  const int nn = min(1 << BSHIFT, N - nbase);
  hist[t] = 0; hist[256 + t] = 0;
  __syncthreads();
  const int p0 = bbase[b], p1 = bbase[b + 1];
  for (int p = p0 + t; p < p1; p += 256) atomicAdd(&hist[pairs[p].x - nbase], 1);
  __syncthreads();
  const int h0 = hist[2 * t], h1 = hist[2 * t + 1];
  const int psum = h0 + h1;
  scan[t] = psum; __syncthreads();
  for (int o = 1; o < 256; o <<= 1) {
    int xx = (t >= o) ? scan[t - o] : 0;
    __syncthreads();
    scan[t] += xx;
    __syncthreads();
  }
  const int ex = scan[t] - psum;   // edges in this bucket before node 2t
  const int li0 = 2 * t, li1 = 2 * t + 1;
  if (li0 < nn) {
    const int i = nbase + li0;
    const int off = p0 + ex + i;
    const float d = rsqrtf((float)(h0 + 1));
    offsets[i] = off; elist[off] = i; lcur[li0] = off + 1;
    dinv[i] = d; sdinv[li0] = d;
  }
  if (li1 < nn) {
    const int i = nbase + li1;
    const int off = p0 + ex + h0 + i;
    const float d = rsqrtf((float)(h1 + 1));
    offsets[i] = off; elist[off] = i; lcur[li1] = off + 1;
    dinv[i] = d; sdinv[li1] = d;
  }
  if (b == NB - 1 && t == 0) offsets[N] = Etot;
  __syncthreads();
  for (int p = p0 + t; p < p1; p += 256) {
    const uint2 pr = pairs[p];
    const int pos = atomicAdd(&lcur[pr.x - nbase], 1);
    elist[pos] = (int)pr.y;
  }
  // fused cast: y rows for this bucket (sdinv visible via the sync above)
  const size_t ebase = (size_t)nbase * 64;
  const int total = nn * 64;
  for (int i = t * 8; i < total; i += 256 * 8) {
    const float d = sdinv[i >> 6];
    f32x4 a = *(const f32x4*)(x + ebase + i);
    f32x4 c = *(const f32x4*)(x + ebase + i + 4);
    u16 o[8];
#pragma unroll
    for (int j = 0; j < 4; j++) { o[j] = f2b(a[j] * d); o[4 + j] = f2b(c[j] * d); }
    *(uint4*)(y + ebase + i) = *(uint4*)o;
  }
}

// ------- GCN aggregation: 2 nodes/wave (half-wave each), 4 groups x 8 lanes per node -------
// y premultiplied by dinv[src]; final scale by dinv[node]. ALL shfls wave-uniform
// (divergent __shfl on CDNA reads undefined data from EXEC-inactive lanes — r5/r6 bug).
__global__ __launch_bounds__(256) void k_agg(const u16* __restrict__ y, const int* __restrict__ offsets,
                                             const int* __restrict__ elist, const float* __restrict__ dinv,
                                             u16* __restrict__ aggx, int n)
{
  const int lane = threadIdx.x & 63;
  const int half = lane >> 5, l32 = lane & 31;
  const int g4 = l32 >> 3, sub = lane & 7;
  const int wid  = (blockIdx.x * 256 + threadIdx.x) >> 6;
  const int nw   = gridDim.x * 4;
  const int npair = (n + 1) >> 1;
  for (int pr = wid; pr < npair; pr += nw) {
    const int node = pr * 2 + half;          // n even -> node < n
    const int s0 = offsets[node], s1 = offsets[node + 1];
    const int mydeg = s1 - s0;
    const int degA = __shfl(mydeg, 0, 64);
    const int degB = __shfl(mydeg, 32, 64);
    const int degmax = max(degA, degB);
    float a[8];
#pragma unroll
    for (int t = 0; t < 8; t++) a[t] = 0.f;
    for (int base = 0; base < degmax; base += 32) {
      const int m = mydeg - base;            // may be <=0 for the finished half
      const int ev = (base + l32 < mydeg) ? elist[s0 + base + l32] : 0;
      const int iters = (min(32, degmax - base) + 3) >> 2;   // wave-uniform
      for (int it = 0; it < iters; it++) {
        const int j = it * 4 + g4;           // 0..31
        const int idx = __shfl(ev, half * 32 + j, 64);   // all lanes active
        if (j < m) {
          const uint4 v = *(const uint4*)(y + (size_t)idx * 64 + sub * 8);
          const u32 w[4] = {v.x, v.y, v.z, v.w};
#pragma unroll
          for (int t = 0; t < 4; t++) {
            a[2 * t]     += b2f((u16)w[t]);
            a[2 * t + 1] += b2f((u16)(w[t] >> 16));
          }
        }
      }
    }
#pragma unroll
    for (int t = 0; t < 8; t++) {
      a[t] += __shfl_xor(a[t], 8, 64);
      a[t] += __shfl_xor(a[t], 16, 64);
    }
    if (g4 == 0) {
      const float di = dinv[node];
      u16 o[8];
#pragma unroll
      for (int t = 0; t < 8; t++) o[t] = f2b(a[t] * di);
      *(uint4*)(aggx + (size_t)node * 64 + sub * 8) = *(uint4*)o;
    }
  }
}

// ---- fold BN0 into W1 (16 blocks x 8 k-rows): W1p = diag(a0)W1 hi/lo T, b1p = c0@W1+b1 ----
__global__ void k_prep1(const float* __restrict__ stats0, const float* __restrict__ W1,
                        const float* __restrict__ b1, const float* __restrict__ g0,
                        const float* __restrict__ be0, u16* __restrict__ W1hiT,
                        u16* __restrict__ W1loT, float* __restrict__ b1p, float n)
{
  __shared__ float A[8], Csh[8];
  const int t = threadIdx.x;  // 128 threads
  if (t < 8) {
    const int k = blockIdx.x * 8 + t;
    const float mu = stats0[k] / n;
    const float var = fmaxf(stats0[128 + k] / n - mu * mu, 0.f);
    const float a = g0[k] * rsqrtf(var + EPS);
    A[t] = a; Csh[t] = be0[k] - mu * a;
  }
  __syncthreads();
  float acc = (blockIdx.x == 0) ? b1[t] : 0.f;
#pragma unroll
  for (int kk = 0; kk < 8; kk++) {
    const int k = blockIdx.x * 8 + kk;
    const float w0 = W1[k * 128 + t];
    acc += Csh[kk] * w0;
    const float w = A[kk] * w0;
    const u16 h = f2b(w);
    W1hiT[t * 128 + k] = h;
    W1loT[t * 128 + k] = f2b(w - b2f(h));
  }
  atomicAdd(&b1p[t], acc);
}

// ---------------- fold BN1/BN2 + concat + W3 into w1f,w2f,constS ----------------
__global__ void k_prep2(const float* __restrict__ stats1, const float* __restrict__ stats2,
                        const float* __restrict__ g1, const float* __restrict__ be1,
                        const float* __restrict__ g2, const float* __restrict__ be2,
                        const float* __restrict__ W3, const float* __restrict__ b3,
                        float* __restrict__ w1f, float* __restrict__ w2f,
                        float* __restrict__ constS, float n)
{
  __shared__ float red[256];
  const int t = threadIdx.x;  // 256 threads
  float c, wv;
  if (t < 128) {
    const float mu = stats1[t] / n;
    const float var = fmaxf(stats1[128 + t] / n - mu * mu, 0.f);
    const float a = g1[t] * rsqrtf(var + EPS);
    c = be1[t] - mu * a;
    wv = W3[t];
    w1f[t] = a * wv;
  } else {
    const int f = t - 128;
    const float mu = stats2[f] / n;
    const float var = fmaxf(stats2[128 + f] / n - mu * mu, 0.f);
    const float a = g2[f] * rsqrtf(var + EPS);
    c = be2[f] - mu * a;
    wv = W3[t];
    w2f[f] = a * wv;
  }
  red[t] = c * wv; __syncthreads();
  for (int o = 128; o; o >>= 1) { if (t < o) red[t] += red[t + o]; __syncthreads(); }
  if (t == 0) { constS[0] = red[0] + b3[0]; constS[1] = b3[0]; }
}

// ---------------- per-graph head from pooled feature sums ----------------
__global__ void k_out2(const float* __restrict__ P1, const float* __restrict__ P2,
                       const int* __restrict__ gofs, const float* __restrict__ w1f,
                       const float* __restrict__ w2f, const float* __restrict__ constS,
                       float* __restrict__ out, int B)
{
  const int lane = threadIdx.x & 63;
  const int g = (blockIdx.x * 256 + threadIdx.x) >> 6;
  if (g >= B) return;
  const int c = gofs[g + 1] - gofs[g];
  const int k = 2 * lane;
  float d = P1[g * 128 + k] * w1f[k] + P1[g * 128 + k + 1] * w1f[k + 1]
          + P2[g * 128 + k] * w2f[k] + P2[g * 128 + k + 1] * w2f[k + 1];
#pragma unroll
  for (int o = 1; o < 64; o <<= 1) d += __shfl_xor(d, o, 64);
  if (lane == 0) out[g] = (c > 0) ? d / (float)c + constS[0] : constS[1];
}

extern "C" void kernel_launch(void* const* d_in, const int* in_sizes, int n_in,
                              void* d_out, int out_size, void* d_ws, size_t ws_size,
                              hipStream_t stream)
{
  const float* x    = (const float*)d_in[0];
  const float* act  = (const float*)d_in[1];
  const float* Wg   = (const float*)d_in[2];
  const float* bg   = (const float*)d_in[3];
  const float* g0   = (const float*)d_in[4];
  const float* be0  = (const float*)d_in[5];
  const float* W1   = (const float*)d_in[6];
  const float* b1   = (const float*)d_in[7];
  const float* g1   = (const float*)d_in[8];
  const float* be1  = (const float*)d_in[9];
  const float* W2   = (const float*)d_in[10];
  const float* b2   = (const float*)d_in[11];
  const float* g2   = (const float*)d_in[12];
  const float* be2  = (const float*)d_in[13];
  const float* W3   = (const float*)d_in[14];
  const float* b3   = (const float*)d_in[15];
  const int* eidx   = (const int*)d_in[16];
  const int* batch  = (const int*)d_in[17];

  const int N = in_sizes[17];          // 200000
  const int E = in_sizes[16] / 2;      // 1600000
  const int B = out_size;              // 1000
  const int* src = eidx;
  const int* dst = eidx + E;
  const int NB = (N + (1 << BSHIFT) - 1) >> BSHIFT;   // ~391 buckets

  char* ws = (char*)d_ws;
  size_t off = 0;
  auto alloc = [&](size_t bytes) -> char* {
    off = (off + 255) & ~(size_t)255;
    char* p = ws + off; off += bytes; return p;
  };

  u16* bufA = (u16*)alloc((size_t)N * 128 * 2);   // h0 (h1/h2 never materialized)
  u16* xb   = (u16*)alloc((size_t)N * 64 * 2);    // y (premult bf16 x)
  u16* aggx = (u16*)alloc((size_t)N * 64 * 2);

  int zwords = 768 + 128 + 2 * NB + 2 * 128 * B;  // stats+b1p+bins + P1+P2
  zwords = (zwords + 7) & ~7;                     // pad for int4-pair zeroing
  char* zbase   = alloc((size_t)zwords * 4);
  float* stats0 = (float*)zbase;
  float* stats1 = stats0 + 256;
  float* stats2 = stats1 + 256;
  float* b1p    = stats2 + 256;
  int*   btot   = (int*)(b1p + 128);
  int*   bcur   = btot + NB;
  float* P1     = (float*)(bcur + NB);            // [B,128] graph sums of h1
  float* P2     = P1 + 128 * B;                   // [B,128] graph sums of h2

  int*   offsets = (int*)alloc((size_t)(N + 1) * 4);
  float* dinv    = (float*)alloc((size_t)N * 4);
  int*   elist   = (int*)alloc((size_t)(E + N) * 4);
  uint2* pairs   = (uint2*)alloc((size_t)E * 8);
  int*   bbase   = (int*)alloc((size_t)(NB + 1) * 4);
  int*   gofs    = (int*)alloc((size_t)(B + 1) * 4);
  u16*   WghiT   = (u16*)alloc(128 * 64 * 2);
  u16*   WgloT   = (u16*)alloc(128 * 64 * 2);
  u16*   W1hiT   = (u16*)alloc(128 * 128 * 2);
  u16*   W1loT   = (u16*)alloc(128 * 128 * 2);
  u16*   W2hiT   = (u16*)alloc(128 * 32 * 2);
  u16*   W2loT   = (u16*)alloc(128 * 32 * 2);
  float* w1f     = (float*)alloc(128 * 4);
  float* w2f     = (float*)alloc(128 * 4);
  float* constS  = (float*)alloc(2 * 4);

  u16* h0 = bufA;

  // prep0: zero scratch (parallel, ~1 MB) + weight split + graph bounds
  const int NZ = (zwords + 2047) / 2048;          // 256 thr x 8 words per block
  const int nbounds = (N + 255) / 256;
  k_prep0<<<NZ + 48 + nbounds, 256, 0, stream>>>(Wg, W2, WghiT, WgloT, W2hiT, W2loT,
                                                 batch, gofs, (int*)zbase, zwords, NZ, N, B);
  // binned edge partition -> per-bucket CSR build + fused x->y cast
  k_bincnt<<<256, 256, NB * 4, stream>>>(dst, btot, E, NB);
  k_exscan<<<1, 256, 0, stream>>>(btot, bbase, NB);
  k_bin<<<256, 256, 2 * NB * 4, stream>>>(src, dst, bbase, bcur, pairs, E, NB);
  k_bucket<<<NB, 256, 0, stream>>>(pairs, bbase, x, offsets, dinv, elist, xb, N, NB, E + N);
  // aggregate, GEMM (+stats0) -> h0
  k_agg<<<2048, 256, 0, stream>>>(xb, offsets, elist, dinv, aggx, N);
  k_gemm<64, true, true, false, false><<<1024, 256, 0, stream>>>(aggx, WghiT, WgloT, bg,
                                                                 h0, stats0, nullptr, nullptr, N);
  // fold BN0 into W1; h1 = relu(h0n @ W1 + b1) pooled into P1 (+stats1)
  k_prep1<<<16, 128, 0, stream>>>(stats0, W1, b1, g0, be0, W1hiT, W1loT, b1p, (float)N);
  k_gemm<128, true, true, false, true><<<1024, 256, 0, stream>>>(h0, W1hiT, W1loT, b1p,
                                                                 nullptr, stats1, batch, P1, N);
  // h2 = relu(action @ W2 + b2) pooled into P2 (+stats2)
  k_gemm<32, true, true, true, true><<<1024, 256, 0, stream>>>(act, W2hiT, W2loT, b2,
                                                               nullptr, stats2, batch, P2, N);
  // fold BN1/BN2 + W3; per-graph head directly from P1/P2
  k_prep2<<<1, 256, 0, stream>>>(stats1, stats2, g1, be1, g2, be2, W3, b3, w1f, w2f, constS, (float)N);
  k_out2<<<(B * 64 + 255) / 256, 256, 0, stream>>>(P1, P2, gofs, w1f, w2f, constS, (float*)d_out, B);
}

// Round 8
// 397.144 us; speedup vs baseline: 1.0089x; 1.0089x over previous
//
#include <hip/hip_runtime.h>

typedef unsigned short u16;
typedef unsigned int   u32;
typedef __bf16 bf16x8 __attribute__((ext_vector_type(8)));
typedef float  f32x4  __attribute__((ext_vector_type(4)));

#define EPS 1e-5f
#define BSHIFT 9               // 512 node ids per bucket

__device__ __forceinline__ float b2f(u16 u){ union{u32 i; float f;} v; v.i=((u32)u)<<16; return v.f; }
__device__ __forceinline__ u16 f2b(float f){
  u32 x = __float_as_uint(f);
  u32 r = x + 0x7fffu + ((x>>16)&1u);   // round-to-nearest-even
  return (u16)(r>>16);
}

// ---- GEMM: C[M,128] = act(A[M,K] @ (Bhi+Blo) + bias), fused per-feature BN stats ----
// v8 = v5 (best: 376us e2e, K128=50.8us, VGPR exactly 128) + grid 768->1024.
// v5 structure: col-split 64-col blocks (<=32KB LDS) + XCD-paired halves
// (b, b+grid/2: 512%8==0 -> same XCD, share A via L2), RT=2 inline static,
// simple 8-atomic/tile POOL epilogue. v7 proved atomics are NOT the floor
// (3x fewer atomics -> slower, because +8 VGPR crossed the 128 cliff: 4->3
// waves/SIMD). This kernel is latency/concurrency-bound; the one lever v5
// left: 4 resident blocks/CU (LDS 33KB*4=133<160; VGPR 16 waves*128=2048=pool).
// NO min-waves launch bound (r2/r4: forced bounds -> scratch spill).
template<int K, bool RELU, bool HASBIAS, bool AF32, bool POOL>
__global__ __launch_bounds__(256) void k_gemm(const void* __restrict__ Av,
                                              const u16* __restrict__ BhiT,
                                              const u16* __restrict__ BloT,
                                              const float* __restrict__ bias,
                                              u16* __restrict__ C,
                                              float* __restrict__ stats,
                                              const int* __restrict__ batch,
                                              float* __restrict__ P, int M)
{
  constexpr int KM = K / 8;                 // 8-elem (16B) blocks per row
  constexpr int KR = K / 32;                // bf16x8 fragments per lane
  __shared__ u16 lds[2 * 64 * K];           // [hi|lo][64 cols][K swizzled]
  __shared__ float sred[64], qred[64];
  const int tid = threadIdx.x;
  const int halfg = gridDim.x >> 1;
  const int ch = (blockIdx.x >= halfg) ? 1 : 0;   // column half: cols ch*64..+63
  const int t0 = blockIdx.x - ch * halfg;         // pair (b, b+halfg): same XCD
  for (int i = tid; i < 64 * KM; i += 256) {
    const int n = i / KM, kb = i % KM;
    const int kb2 = kb ^ (n & (KM - 1));
    const int gsrc = ((ch * 64 + n) * KM + kb) * 8;
    *(uint4*)(&lds[(n * KM + kb2) * 8])          = *(const uint4*)(BhiT + gsrc);
    *(uint4*)(&lds[64 * K + (n * KM + kb2) * 8]) = *(const uint4*)(BloT + gsrc);
  }
  if (tid < 64) { sred[tid] = 0.f; qred[tid] = 0.f; }
  __syncthreads();
  const int wid = tid >> 6, lane = tid & 63, q = lane >> 4, r16 = lane & 15;
  const int nmt = (M + 127) >> 7;           // 128-row macro tiles (M % 64 == 0)
  float ls[4], lq[4];
#pragma unroll
  for (int nb = 0; nb < 4; nb++) { ls[nb] = 0.f; lq[nb] = 0.f; }
  float bv[4];
#pragma unroll
  for (int nb = 0; nb < 4; nb++) bv[nb] = HASBIAS ? bias[ch * 64 + nb * 16 + r16] : 0.f;

  for (int mt = t0; mt < nmt; mt += halfg) {
    const int row0 = mt << 7;               // rt=0 rows always valid
    const bool ok1 = (row0 + 64) < M;       // rt=1 rows row0+64..127

    bf16x8 av[2][KR];
    if (AF32) {
      const float* Af = (const float*)Av + (size_t)(row0 + (wid << 4) + r16) * K + q * 8;
#pragma unroll
      for (int kk = 0; kk < KR; kk++) {
        f32x4 x0 = *(const f32x4*)(Af + kk * 32);
        f32x4 x1 = *(const f32x4*)(Af + kk * 32 + 4);
#pragma unroll
        for (int j = 0; j < 4; j++) { av[0][kk][j] = (__bf16)x0[j]; av[0][kk][4 + j] = (__bf16)x1[j]; }
      }
      if (ok1) {
        const float* Ag = Af + (size_t)64 * K;
#pragma unroll
        for (int kk = 0; kk < KR; kk++) {
          f32x4 x0 = *(const f32x4*)(Ag + kk * 32);
          f32x4 x1 = *(const f32x4*)(Ag + kk * 32 + 4);
#pragma unroll
          for (int j = 0; j < 4; j++) { av[1][kk][j] = (__bf16)x0[j]; av[1][kk][4 + j] = (__bf16)x1[j]; }
        }
      }
    } else {
      const u16* Ab = (const u16*)Av + (size_t)(row0 + (wid << 4) + r16) * K + q * 8;
#pragma unroll
      for (int kk = 0; kk < KR; kk++) av[0][kk] = *(const bf16x8*)(Ab + kk * 32);
      if (ok1) {
#pragma unroll
        for (int kk = 0; kk < KR; kk++) av[1][kk] = *(const bf16x8*)(Ab + (size_t)64 * K + kk * 32);
      }
    }

    f32x4 acc[2][4];
#pragma unroll
    for (int rt = 0; rt < 2; rt++)
#pragma unroll
      for (int nb = 0; nb < 4; nb++) acc[rt][nb] = (f32x4){0.f, 0.f, 0.f, 0.f};
#pragma unroll
    for (int kk = 0; kk < KR; kk++) {
#pragma unroll
      for (int nb = 0; nb < 4; nb++) {
        const int n = nb * 16 + r16;
        const int kb2 = (kk * 4 + q) ^ (n & (KM - 1));
        const bf16x8 bh = *(const bf16x8*)(&lds[(n * KM + kb2) * 8]);
        const bf16x8 bl = *(const bf16x8*)(&lds[64 * K + (n * KM + kb2) * 8]);
        acc[0][nb] = __builtin_amdgcn_mfma_f32_16x16x32_bf16(av[0][kk], bh, acc[0][nb], 0, 0, 0);
        acc[0][nb] = __builtin_amdgcn_mfma_f32_16x16x32_bf16(av[0][kk], bl, acc[0][nb], 0, 0, 0);
        if (ok1) {
          acc[1][nb] = __builtin_amdgcn_mfma_f32_16x16x32_bf16(av[1][kk], bh, acc[1][nb], 0, 0, 0);
          acc[1][nb] = __builtin_amdgcn_mfma_f32_16x16x32_bf16(av[1][kk], bl, acc[1][nb], 0, 0, 0);
        }
      }
    }

#pragma unroll
    for (int rt = 0; rt < 2; rt++) {
      if (rt && !ok1) continue;
      const int rbase = row0 + rt * 64 + (wid << 4) + (q << 2);
#pragma unroll
      for (int nb = 0; nb < 4; nb++) {
        const int col = ch * 64 + nb * 16 + r16;
#pragma unroll
        for (int r = 0; r < 4; r++) {
          float v = acc[rt][nb][r] + bv[nb];
          if (RELU) v = fmaxf(v, 0.f);
          ls[nb] += v; lq[nb] += v * v;
          if (!POOL) C[(size_t)(rbase + r) * 128 + col] = f2b(v);
          else acc[rt][nb][r] = v;
        }
      }
      if (POOL) {
        int bg[4];
#pragma unroll
        for (int r = 0; r < 4; r++) bg[r] = batch[rbase + r];
        const int g0 = __shfl(bg[0], 0, 64);    // batch[first row of wave tile]
        const int g1 = __shfl(bg[3], 48, 64);   // batch[last row of wave tile]
        for (int g = g0; g <= g1; ++g) {        // wave-uniform, almost always 1 iter
#pragma unroll
          for (int nb = 0; nb < 4; nb++) {
            float sv = 0.f;
#pragma unroll
            for (int r = 0; r < 4; r++) sv += (bg[r] == g) ? acc[rt][nb][r] : 0.f;
            sv += __shfl_xor(sv, 16, 64);       // sum the 4 q-groups (16 rows)
            sv += __shfl_xor(sv, 32, 64);
            if (q == 0) atomicAdd(&P[g * 128 + ch * 64 + nb * 16 + r16], sv);
          }
        }
      }
    }
  }
#pragma unroll
  for (int nb = 0; nb < 4; nb++) {
    atomicAdd(&sred[nb * 16 + r16], ls[nb]);
    atomicAdd(&qred[nb * 16 + r16], lq[nb]);
  }
  __syncthreads();
  if (tid < 64) {
    atomicAdd(&stats[ch * 64 + tid], sred[tid]);
    atomicAdd(&stats[128 + ch * 64 + tid], qred[tid]);
  }
}

// ---- prep0: blocks [0,NZ) zero scratch; [NZ,NZ+48) split Wg/W2 hi/lo T; rest: bounds ----
__global__ void k_prep0(const float* __restrict__ Wg, const float* __restrict__ W2,
                        u16* __restrict__ WghiT, u16* __restrict__ WgloT,
                        u16* __restrict__ W2hiT, u16* __restrict__ W2loT,
                        const int* __restrict__ batch, int* __restrict__ gofs,
                        int* __restrict__ zbase, int zwords, int NZ, int N, int B)
{
  const int bid = blockIdx.x, t = threadIdx.x;
  if (bid < NZ) {
    const int i = bid * 2048 + t * 8;       // zwords padded to multiple of 8
    if (i < zwords) {
      *(int4*)(zbase + i)     = make_int4(0, 0, 0, 0);
      *(int4*)(zbase + i + 4) = make_int4(0, 0, 0, 0);
    }
  } else if (bid < NZ + 48) {
    const int i = (bid - NZ) * 256 + t;
    if (i < 64 * 128) {
      int k = i >> 7, n = i & 127;
      float w = Wg[i]; u16 h = f2b(w);
      WghiT[n * 64 + k] = h; WgloT[n * 64 + k] = f2b(w - b2f(h));
    } else if (i < 64 * 128 + 32 * 128) {
      int j = i - 64 * 128;
      int k = j >> 7, n = j & 127;
      float w = W2[j]; u16 h = f2b(w);
      W2hiT[n * 32 + k] = h; W2loT[n * 32 + k] = f2b(w - b2f(h));
    }
  } else {
    const int i = (bid - NZ - 48) * 256 + t;
    if (i == 0) { for (int g = 0; g <= batch[0]; g++) gofs[g] = 0; }
    if (i == N - 1) { for (int g = batch[N - 1] + 1; g <= B; g++) gofs[g] = N; }
    if (i < N - 1) {
      const int b0 = batch[i], b1 = batch[i + 1];
      for (int g = b0 + 1; g <= b1; g++) gofs[g] = i + 1;
    }
  }
}

// ========== binned edge partition ==========
__global__ __launch_bounds__(256) void k_bincnt(const int* __restrict__ dst, int* __restrict__ btot,
                                                int E, int NB)
{
  extern __shared__ int hist[];
  const int tid = threadIdx.x;
  for (int i = tid; i < NB; i += 256) hist[i] = 0;
  __syncthreads();
  const int chunk = (E + gridDim.x - 1) / gridDim.x;
  const int start = blockIdx.x * chunk;
  const int end = min(start + chunk, E);
  for (int e = start + tid; e < end; e += 256) atomicAdd(&hist[((u32)dst[e]) >> BSHIFT], 1);
  __syncthreads();
  for (int i = tid; i < NB; i += 256) if (hist[i]) atomicAdd(&btot[i], hist[i]);
}

// single-block exclusive scan; out[0..n-1] = exclusive, out[n] = total
__global__ void k_exscan(const int* __restrict__ in, int* __restrict__ out, int n)
{
  __shared__ int s[256];
  const int t = threadIdx.x;
  const int per = (n + 255) / 256;
  const int base = t * per;
  int loc[8]; int sum = 0;
  for (int j = 0; j < per; j++) { int v = (base + j < n) ? in[base + j] : 0; loc[j] = sum; sum += v; }
  s[t] = sum; __syncthreads();
  for (int o = 1; o < 256; o <<= 1) {
    int x = (t >= o) ? s[t - o] : 0;
    __syncthreads();
    s[t] += x;
    __syncthreads();
  }
  const int ex = s[t] - sum;
  for (int j = 0; j < per; j++) if (base + j < n) out[base + j] = ex + loc[j];
  if (t == 255) out[n] = s[255];
}

// re-read edges, reserve per-(block,bucket) ranges, stream (dst,src) pairs
__global__ __launch_bounds__(256) void k_bin(const int* __restrict__ src, const int* __restrict__ dst,
                                             const int* __restrict__ bbase, int* __restrict__ bcur,
                                             uint2* __restrict__ pairs, int E, int NB)
{
  extern __shared__ int lds[];
  int* hist = lds; int* wbase = lds + NB;
  const int tid = threadIdx.x;
  for (int i = tid; i < NB; i += 256) hist[i] = 0;
  __syncthreads();
  const int chunk = (E + gridDim.x - 1) / gridDim.x;
  const int start = blockIdx.x * chunk;
  const int end = min(start + chunk, E);
  for (int e = start + tid; e < end; e += 256) atomicAdd(&hist[((u32)dst[e]) >> BSHIFT], 1);
  __syncthreads();
  for (int i = tid; i < NB; i += 256) {
    int c = hist[i];
    wbase[i] = c ? bbase[i] + atomicAdd(&bcur[i], c) : 0;
    hist[i] = 0;
  }
  __syncthreads();
  for (int e = start + tid; e < end; e += 256) {
    const int d = dst[e];
    const int b = ((u32)d) >> BSHIFT;
    const int o = atomicAdd(&hist[b], 1);
    pairs[wbase[b] + o] = make_uint2((u32)d, (u32)src[e]);
  }
}

// ---- per-bucket: degree hist -> LDS scan -> offsets/dinv/self-loop -> scatter ----
// Also fused: y[i] = bf16(x[i] * dinv[i]) for the bucket's own 512 nodes (coalesced).
__global__ __launch_bounds__(256) void k_bucket(const uint2* __restrict__ pairs,
                                                const int* __restrict__ bbase,
                                                const float* __restrict__ x,
                                                int* __restrict__ offsets, float* __restrict__ dinv,
                                                int* __restrict__ elist, u16* __restrict__ y,
                                                int N, int NB, int Etot)
{
  __shared__ int hist[512];
  __shared__ int scan[256];
  __shared__ int lcur[512];
  __shared__ float sdinv[512];
  const int b = blockIdx.x, t = threadIdx.x;
  const int nbase = b << BSHIFT;
  const int nn = min(1 << BSHIFT, N - nbase);
  hist[t] = 0; hist[256 + t] = 0;
  __syncthreads();
  const int p0 = bbase[b], p1 = bbase[b + 1];
  for (int p = p0 + t; p < p1; p += 256) atomicAdd(&hist[pairs[p].x - nbase], 1);
  __syncthreads();
  const int h0 = hist[2 * t], h1 = hist[2 * t + 1];
  const int psum = h0 + h1;
  scan[t] = psum; __syncthreads();
  for (int o = 1; o < 256; o <<= 1) {
    int xx = (t >= o) ? scan[t - o] : 0;
    __syncthreads();
    scan[t] += xx;
    __syncthreads();
  }
  const int ex = scan[t] - psum;   // edges in this bucket before node 2t
  const int li0 = 2 * t, li1 = 2 * t + 1;
  if (li0 < nn) {
    const int i = nbase + li0;
    const int off = p0 + ex + i;
    const float d = rsqrtf((float)(h0 + 1));
    offsets[i] = off; elist[off] = i; lcur[li0] = off + 1;
    dinv[i] = d; sdinv[li0] = d;
  }
  if (li1 < nn) {
    const int i = nbase + li1;
    const int off = p0 + ex + h0 + i;
    const float d = rsqrtf((float)(h1 + 1));
    offsets[i] = off; elist[off] = i; lcur[li1] = off + 1;
    dinv[i] = d; sdinv[li1] = d;
  }
  if (b == NB - 1 && t == 0) offsets[N] = Etot;
  __syncthreads();
  for (int p = p0 + t; p < p1; p += 256) {
    const uint2 pr = pairs[p];
    const int pos = atomicAdd(&lcur[pr.x - nbase], 1);
    elist[pos] = (int)pr.y;
  }
  // fused cast: y rows for this bucket (sdinv visible via the sync above)
  const size_t ebase = (size_t)nbase * 64;
  const int total = nn * 64;
  for (int i = t * 8; i < total; i += 256 * 8) {
    const float d = sdinv[i >> 6];
    f32x4 a = *(const f32x4*)(x + ebase + i);
    f32x4 c = *(const f32x4*)(x + ebase + i + 4);
    u16 o[8];
#pragma unroll
    for (int j = 0; j < 4; j++) { o[j] = f2b(a[j] * d); o[4 + j] = f2b(c[j] * d); }
    *(uint4*)(y + ebase + i) = *(uint4*)o;
  }
}

// ------- GCN aggregation: 2 nodes/wave (half-wave each), 4 groups x 8 lanes per node -------
// y premultiplied by dinv[src]; final scale by dinv[node]. ALL shfls wave-uniform
// (divergent __shfl on CDNA reads undefined data from EXEC-inactive lanes — r5/r6 bug).
__global__ __launch_bounds__(256) void k_agg(const u16* __restrict__ y, const int* __restrict__ offsets,
                                             const int* __restrict__ elist, const float* __restrict__ dinv,
                                             u16* __restrict__ aggx, int n)
{
  const int lane = threadIdx.x & 63;
  const int half = lane >> 5, l32 = lane & 31;
  const int g4 = l32 >> 3, sub = lane & 7;
  const int wid  = (blockIdx.x * 256 + threadIdx.x) >> 6;
  const int nw   = gridDim.x * 4;
  const int npair = (n + 1) >> 1;
  for (int pr = wid; pr < npair; pr += nw) {
    const int node = pr * 2 + half;          // n even -> node < n
    const int s0 = offsets[node], s1 = offsets[node + 1];
    const int mydeg = s1 - s0;
    const int degA = __shfl(mydeg, 0, 64);
    const int degB = __shfl(mydeg, 32, 64);
    const int degmax = max(degA, degB);
    float a[8];
#pragma unroll
    for (int t = 0; t < 8; t++) a[t] = 0.f;
    for (int base = 0; base < degmax; base += 32) {
      const int m = mydeg - base;            // may be <=0 for the finished half
      const int ev = (base + l32 < mydeg) ? elist[s0 + base + l32] : 0;
      const int iters = (min(32, degmax - base) + 3) >> 2;   // wave-uniform
      for (int it = 0; it < iters; it++) {
        const int j = it * 4 + g4;           // 0..31
        const int idx = __shfl(ev, half * 32 + j, 64);   // all lanes active
        if (j < m) {
          const uint4 v = *(const uint4*)(y + (size_t)idx * 64 + sub * 8);
          const u32 w[4] = {v.x, v.y, v.z, v.w};
#pragma unroll
          for (int t = 0; t < 4; t++) {
            a[2 * t]     += b2f((u16)w[t]);
            a[2 * t + 1] += b2f((u16)(w[t] >> 16));
          }
        }
      }
    }
#pragma unroll
    for (int t = 0; t < 8; t++) {
      a[t] += __shfl_xor(a[t], 8, 64);
      a[t] += __shfl_xor(a[t], 16, 64);
    }
    if (g4 == 0) {
      const float di = dinv[node];
      u16 o[8];
#pragma unroll
      for (int t = 0; t < 8; t++) o[t] = f2b(a[t] * di);
      *(uint4*)(aggx + (size_t)node * 64 + sub * 8) = *(uint4*)o;
    }
  }
}

// ---- fold BN0 into W1 (16 blocks x 8 k-rows): W1p = diag(a0)W1 hi/lo T, b1p = c0@W1+b1 ----
__global__ void k_prep1(const float* __restrict__ stats0, const float* __restrict__ W1,
                        const float* __restrict__ b1, const float* __restrict__ g0,
                        const float* __restrict__ be0, u16* __restrict__ W1hiT,
                        u16* __restrict__ W1loT, float* __restrict__ b1p, float n)
{
  __shared__ float A[8], Csh[8];
  const int t = threadIdx.x;  // 128 threads
  if (t < 8) {
    const int k = blockIdx.x * 8 + t;
    const float mu = stats0[k] / n;
    const float var = fmaxf(stats0[128 + k] / n - mu * mu, 0.f);
    const float a = g0[k] * rsqrtf(var + EPS);
    A[t] = a; Csh[t] = be0[k] - mu * a;
  }
  __syncthreads();
  float acc = (blockIdx.x == 0) ? b1[t] : 0.f;
#pragma unroll
  for (int kk = 0; kk < 8; kk++) {
    const int k = blockIdx.x * 8 + kk;
    const float w0 = W1[k * 128 + t];
    acc += Csh[kk] * w0;
    const float w = A[kk] * w0;
    const u16 h = f2b(w);
    W1hiT[t * 128 + k] = h;
    W1loT[t * 128 + k] = f2b(w - b2f(h));
  }
  atomicAdd(&b1p[t], acc);
}

// ---------------- fold BN1/BN2 + concat + W3 into w1f,w2f,constS ----------------
__global__ void k_prep2(const float* __restrict__ stats1, const float* __restrict__ stats2,
                        const float* __restrict__ g1, const float* __restrict__ be1,
                        const float* __restrict__ g2, const float* __restrict__ be2,
                        const float* __restrict__ W3, const float* __restrict__ b3,
                        float* __restrict__ w1f, float* __restrict__ w2f,
                        float* __restrict__ constS, float n)
{
  __shared__ float red[256];
  const int t = threadIdx.x;  // 256 threads
  float c, wv;
  if (t < 128) {
    const float mu = stats1[t] / n;
    const float var = fmaxf(stats1[128 + t] / n - mu * mu, 0.f);
    const float a = g1[t] * rsqrtf(var + EPS);
    c = be1[t] - mu * a;
    wv = W3[t];
    w1f[t] = a * wv;
  } else {
    const int f = t - 128;
    const float mu = stats2[f] / n;
    const float var = fmaxf(stats2[128 + f] / n - mu * mu, 0.f);
    const float a = g2[f] * rsqrtf(var + EPS);
    c = be2[f] - mu * a;
    wv = W3[t];
    w2f[f] = a * wv;
  }
  red[t] = c * wv; __syncthreads();
  for (int o = 128; o; o >>= 1) { if (t < o) red[t] += red[t + o]; __syncthreads(); }
  if (t == 0) { constS[0] = red[0] + b3[0]; constS[1] = b3[0]; }
}

// ---------------- per-graph head from pooled feature sums ----------------
__global__ void k_out2(const float* __restrict__ P1, const float* __restrict__ P2,
                       const int* __restrict__ gofs, const float* __restrict__ w1f,
                       const float* __restrict__ w2f, const float* __restrict__ constS,
                       float* __restrict__ out, int B)
{
  const int lane = threadIdx.x & 63;
  const int g = (blockIdx.x * 256 + threadIdx.x) >> 6;
  if (g >= B) return;
  const int c = gofs[g + 1] - gofs[g];
  const int k = 2 * lane;
  float d = P1[g * 128 + k] * w1f[k] + P1[g * 128 + k + 1] * w1f[k + 1]
          + P2[g * 128 + k] * w2f[k] + P2[g * 128 + k + 1] * w2f[k + 1];
#pragma unroll
  for (int o = 1; o < 64; o <<= 1) d += __shfl_xor(d, o, 64);
  if (lane == 0) out[g] = (c > 0) ? d / (float)c + constS[0] : constS[1];
}

extern "C" void kernel_launch(void* const* d_in, const int* in_sizes, int n_in,
                              void* d_out, int out_size, void* d_ws, size_t ws_size,
                              hipStream_t stream)
{
  const float* x    = (const float*)d_in[0];
  const float* act  = (const float*)d_in[1];
  const float* Wg   = (const float*)d_in[2];
  const float* bg   = (const float*)d_in[3];
  const float* g0   = (const float*)d_in[4];
  const float* be0  = (const float*)d_in[5];
  const float* W1   = (const float*)d_in[6];
  const float* b1   = (const float*)d_in[7];
  const float* g1   = (const float*)d_in[8];
  const float* be1  = (const float*)d_in[9];
  const float* W2   = (const float*)d_in[10];
  const float* b2   = (const float*)d_in[11];
  const float* g2   = (const float*)d_in[12];
  const float* be2  = (const float*)d_in[13];
  const float* W3   = (const float*)d_in[14];
  const float* b3   = (const float*)d_in[15];
  const int* eidx   = (const int*)d_in[16];
  const int* batch  = (const int*)d_in[17];

  const int N = in_sizes[17];          // 200000
  const int E = in_sizes[16] / 2;      // 1600000
  const int B = out_size;              // 1000
  const int* src = eidx;
  const int* dst = eidx + E;
  const int NB = (N + (1 << BSHIFT) - 1) >> BSHIFT;   // ~391 buckets

  char* ws = (char*)d_ws;
  size_t off = 0;
  auto alloc = [&](size_t bytes) -> char* {
    off = (off + 255) & ~(size_t)255;
    char* p = ws + off; off += bytes; return p;
  };

  u16* bufA = (u16*)alloc((size_t)N * 128 * 2);   // h0 (h1/h2 never materialized)
  u16* xb   = (u16*)alloc((size_t)N * 64 * 2);    // y (premult bf16 x)
  u16* aggx = (u16*)alloc((size_t)N * 64 * 2);

  int zwords = 768 + 128 + 2 * NB + 2 * 128 * B;  // stats+b1p+bins + P1+P2
  zwords = (zwords + 7) & ~7;                     // pad for int4-pair zeroing
  char* zbase   = alloc((size_t)zwords * 4);
  float* stats0 = (float*)zbase;
  float* stats1 = stats0 + 256;
  float* stats2 = stats1 + 256;
  float* b1p    = stats2 + 256;
  int*   btot   = (int*)(b1p + 128);
  int*   bcur   = btot + NB;
  float* P1     = (float*)(bcur + NB);            // [B,128] graph sums of h1
  float* P2     = P1 + 128 * B;                   // [B,128] graph sums of h2

  int*   offsets = (int*)alloc((size_t)(N + 1) * 4);
  float* dinv    = (float*)alloc((size_t)N * 4);
  int*   elist   = (int*)alloc((size_t)(E + N) * 4);
  uint2* pairs   = (uint2*)alloc((size_t)E * 8);
  int*   bbase   = (int*)alloc((size_t)(NB + 1) * 4);
  int*   gofs    = (int*)alloc((size_t)(B + 1) * 4);
  u16*   WghiT   = (u16*)alloc(128 * 64 * 2);
  u16*   WgloT   = (u16*)alloc(128 * 64 * 2);
  u16*   W1hiT   = (u16*)alloc(128 * 128 * 2);
  u16*   W1loT   = (u16*)alloc(128 * 128 * 2);
  u16*   W2hiT   = (u16*)alloc(128 * 32 * 2);
  u16*   W2loT   = (u16*)alloc(128 * 32 * 2);
  float* w1f     = (float*)alloc(128 * 4);
  float* w2f     = (float*)alloc(128 * 4);
  float* constS  = (float*)alloc(2 * 4);

  u16* h0 = bufA;

  // prep0: zero scratch (parallel, ~1 MB) + weight split + graph bounds
  const int NZ = (zwords + 2047) / 2048;          // 256 thr x 8 words per block
  const int nbounds = (N + 255) / 256;
  k_prep0<<<NZ + 48 + nbounds, 256, 0, stream>>>(Wg, W2, WghiT, WgloT, W2hiT, W2loT,
                                                 batch, gofs, (int*)zbase, zwords, NZ, N, B);
  // binned edge partition -> per-bucket CSR build + fused x->y cast
  k_bincnt<<<256, 256, NB * 4, stream>>>(dst, btot, E, NB);
  k_exscan<<<1, 256, 0, stream>>>(btot, bbase, NB);
  k_bin<<<256, 256, 2 * NB * 4, stream>>>(src, dst, bbase, bcur, pairs, E, NB);
  k_bucket<<<NB, 256, 0, stream>>>(pairs, bbase, x, offsets, dinv, elist, xb, N, NB, E + N);
  // aggregate, GEMM (+stats0) -> h0
  k_agg<<<2048, 256, 0, stream>>>(xb, offsets, elist, dinv, aggx, N);
  k_gemm<64, true, true, false, false><<<1024, 256, 0, stream>>>(aggx, WghiT, WgloT, bg,
                                                                 h0, stats0, nullptr, nullptr, N);
  // fold BN0 into W1; h1 = relu(h0n @ W1 + b1) pooled into P1 (+stats1)
  k_prep1<<<16, 128, 0, stream>>>(stats0, W1, b1, g0, be0, W1hiT, W1loT, b1p, (float)N);
  k_gemm<128, true, true, false, true><<<1024, 256, 0, stream>>>(h0, W1hiT, W1loT, b1p,
                                                                 nullptr, stats1, batch, P1, N);
  // h2 = relu(action @ W2 + b2) pooled into P2 (+stats2)
  k_gemm<32, true, true, true, true><<<1024, 256, 0, stream>>>(act, W2hiT, W2loT, b2,
                                                               nullptr, stats2, batch, P2, N);
  // fold BN1/BN2 + W3; per-graph head directly from P1/P2
  k_prep2<<<1, 256, 0, stream>>>(stats1, stats2, g1, be1, g2, be2, W3, b3, w1f, w2f, constS, (float)N);
  k_out2<<<(B * 64 + 255) / 256, 256, 0, stream>>>(P1, P2, gofs, w1f, w2f, constS, (float*)d_out, B);
}

// Round 10
// 372.055 us; speedup vs baseline: 1.0770x; 1.0674x over previous
//
#include <hip/hip_runtime.h>

typedef unsigned short u16;
typedef unsigned int   u32;
typedef __bf16 bf16x8 __attribute__((ext_vector_type(8)));
typedef float  f32x4  __attribute__((ext_vector_type(4)));

#define EPS 1e-5f
#define BSHIFT 9               // 512 node ids per bucket

__device__ __forceinline__ float b2f(u16 u){ union{u32 i; float f;} v; v.i=((u32)u)<<16; return v.f; }
__device__ __forceinline__ u16 f2b(float f){
  u32 x = __float_as_uint(f);
  u32 r = x + 0x7fffu + ((x>>16)&1u);   // round-to-nearest-even
  return (u16)(r>>16);
}

// ---- GEMM body: C[M,128] = act(A[M,K] @ (Bhi+Blo) + bias), fused BN stats ----
// v10 = v9 resubmit (round-9 bench was the same infra error string as round 6,
// which passed unchanged on resubmit in round 7; code audit found no hang path).
// v5 structure exactly (best: 376us e2e, K128=50.8us, VGPR 128, grid 768):
// col-split 64-col blocks + XCD-paired halves (stride%8==0 -> same XCD), RT=2
// inline static, simple POOL epilogue. __device__ body with extern-shared LDS
// and explicit (bid, halfg) so independent GEMMs can FUSE into one dispatch
// (r8: each GEMM ~90% idle on every pipe -> overlap them, don't serialize).
// Ledger: forced launch_bounds -> spill (r2/r4); fewer atomics -> slower (r7);
// more blocks/CU -> slower, FETCH-correlated (r8). Do not revisit.
template<int K, bool RELU, bool HASBIAS, bool AF32, bool POOL>
__device__ __forceinline__ void gemm_body(const void* __restrict__ Av,
                                          const u16* __restrict__ BhiT,
                                          const u16* __restrict__ BloT,
                                          const float* __restrict__ bias,
                                          u16* __restrict__ C,
                                          float* __restrict__ stats,
                                          const int* __restrict__ batch,
                                          float* __restrict__ P, int M,
                                          int bid, int halfg)
{
  constexpr int KM = K / 8;                 // 8-elem (16B) blocks per row
  constexpr int KR = K / 32;                // bf16x8 fragments per lane
  extern __shared__ char smem[];
  u16* lds    = (u16*)smem;                 // [hi|lo][64 cols][K swizzled]
  float* sred = (float*)(smem + (size_t)2 * 64 * K * 2);
  float* qred = sred + 64;
  const int tid = threadIdx.x;
  const int ch = (bid >= halfg) ? 1 : 0;    // column half: cols ch*64..+63
  const int t0 = bid - ch * halfg;          // pair (b, b+halfg): same XCD
  for (int i = tid; i < 64 * KM; i += 256) {
    const int n = i / KM, kb = i % KM;
    const int kb2 = kb ^ (n & (KM - 1));
    const int gsrc = ((ch * 64 + n) * KM + kb) * 8;
    *(uint4*)(&lds[(n * KM + kb2) * 8])          = *(const uint4*)(BhiT + gsrc);
    *(uint4*)(&lds[64 * K + (n * KM + kb2) * 8]) = *(const uint4*)(BloT + gsrc);
  }
  if (tid < 64) { sred[tid] = 0.f; qred[tid] = 0.f; }
  __syncthreads();
  const int wid = tid >> 6, lane = tid & 63, q = lane >> 4, r16 = lane & 15;
  const int nmt = (M + 127) >> 7;           // 128-row macro tiles (M % 64 == 0)
  float ls[4], lq[4];
#pragma unroll
  for (int nb = 0; nb < 4; nb++) { ls[nb] = 0.f; lq[nb] = 0.f; }
  float bv[4];
#pragma unroll
  for (int nb = 0; nb < 4; nb++) bv[nb] = HASBIAS ? bias[ch * 64 + nb * 16 + r16] : 0.f;

  for (int mt = t0; mt < nmt; mt += halfg) {
    const int row0 = mt << 7;               // rt=0 rows always valid
    const bool ok1 = (row0 + 64) < M;       // rt=1 rows row0+64..127

    bf16x8 av[2][KR];
    if (AF32) {
      const float* Af = (const float*)Av + (size_t)(row0 + (wid << 4) + r16) * K + q * 8;
#pragma unroll
      for (int kk = 0; kk < KR; kk++) {
        f32x4 x0 = *(const f32x4*)(Af + kk * 32);
        f32x4 x1 = *(const f32x4*)(Af + kk * 32 + 4);
#pragma unroll
        for (int j = 0; j < 4; j++) { av[0][kk][j] = (__bf16)x0[j]; av[0][kk][4 + j] = (__bf16)x1[j]; }
      }
      if (ok1) {
        const float* Ag = Af + (size_t)64 * K;
#pragma unroll
        for (int kk = 0; kk < KR; kk++) {
          f32x4 x0 = *(const f32x4*)(Ag + kk * 32);
          f32x4 x1 = *(const f32x4*)(Ag + kk * 32 + 4);
#pragma unroll
          for (int j = 0; j < 4; j++) { av[1][kk][j] = (__bf16)x0[j]; av[1][kk][4 + j] = (__bf16)x1[j]; }
        }
      }
    } else {
      const u16* Ab = (const u16*)Av + (size_t)(row0 + (wid << 4) + r16) * K + q * 8;
#pragma unroll
      for (int kk = 0; kk < KR; kk++) av[0][kk] = *(const bf16x8*)(Ab + kk * 32);
      if (ok1) {
#pragma unroll
        for (int kk = 0; kk < KR; kk++) av[1][kk] = *(const bf16x8*)(Ab + (size_t)64 * K + kk * 32);
      }
    }

    f32x4 acc[2][4];
#pragma unroll
    for (int rt = 0; rt < 2; rt++)
#pragma unroll
      for (int nb = 0; nb < 4; nb++) acc[rt][nb] = (f32x4){0.f, 0.f, 0.f, 0.f};
#pragma unroll
    for (int kk = 0; kk < KR; kk++) {
#pragma unroll
      for (int nb = 0; nb < 4; nb++) {
        const int n = nb * 16 + r16;
        const int kb2 = (kk * 4 + q) ^ (n & (KM - 1));
        const bf16x8 bh = *(const bf16x8*)(&lds[(n * KM + kb2) * 8]);
        const bf16x8 bl = *(const bf16x8*)(&lds[64 * K + (n * KM + kb2) * 8]);
        acc[0][nb] = __builtin_amdgcn_mfma_f32_16x16x32_bf16(av[0][kk], bh, acc[0][nb], 0, 0, 0);
        acc[0][nb] = __builtin_amdgcn_mfma_f32_16x16x32_bf16(av[0][kk], bl, acc[0][nb], 0, 0, 0);
        if (ok1) {
          acc[1][nb] = __builtin_amdgcn_mfma_f32_16x16x32_bf16(av[1][kk], bh, acc[1][nb], 0, 0, 0);
          acc[1][nb] = __builtin_amdgcn_mfma_f32_16x16x32_bf16(av[1][kk], bl, acc[1][nb], 0, 0, 0);
        }
      }
    }

#pragma unroll
    for (int rt = 0; rt < 2; rt++) {
      if (rt && !ok1) continue;
      const int rbase = row0 + rt * 64 + (wid << 4) + (q << 2);
#pragma unroll
      for (int nb = 0; nb < 4; nb++) {
        const int col = ch * 64 + nb * 16 + r16;
#pragma unroll
        for (int r = 0; r < 4; r++) {
          float v = acc[rt][nb][r] + bv[nb];
          if (RELU) v = fmaxf(v, 0.f);
          ls[nb] += v; lq[nb] += v * v;
          if (!POOL) C[(size_t)(rbase + r) * 128 + col] = f2b(v);
          else acc[rt][nb][r] = v;
        }
      }
      if (POOL) {
        int bg[4];
#pragma unroll
        for (int r = 0; r < 4; r++) bg[r] = batch[rbase + r];
        const int g0 = __shfl(bg[0], 0, 64);    // batch[first row of wave tile]
        const int g1 = __shfl(bg[3], 48, 64);   // batch[last row of wave tile]
        for (int g = g0; g <= g1; ++g) {        // wave-uniform, almost always 1 iter
#pragma unroll
          for (int nb = 0; nb < 4; nb++) {
            float sv = 0.f;
#pragma unroll
            for (int r = 0; r < 4; r++) sv += (bg[r] == g) ? acc[rt][nb][r] : 0.f;
            sv += __shfl_xor(sv, 16, 64);       // sum the 4 q-groups (16 rows)
            sv += __shfl_xor(sv, 32, 64);
            if (q == 0) atomicAdd(&P[g * 128 + ch * 64 + nb * 16 + r16], sv);
          }
        }
      }
    }
  }
#pragma unroll
  for (int nb = 0; nb < 4; nb++) {
    atomicAdd(&sred[nb * 16 + r16], ls[nb]);
    atomicAdd(&qred[nb * 16 + r16], lq[nb]);
  }
  __syncthreads();
  if (tid < 64) {
    atomicAdd(&stats[ch * 64 + tid], sred[tid]);
    atomicAdd(&stats[128 + ch * 64 + tid], qred[tid]);
  }
}

template<int K, bool RELU, bool HASBIAS, bool AF32, bool POOL>
__global__ __launch_bounds__(256) void k_gemm(const void* __restrict__ Av,
                                              const u16* __restrict__ BhiT,
                                              const u16* __restrict__ BloT,
                                              const float* __restrict__ bias,
                                              u16* __restrict__ C,
                                              float* __restrict__ stats,
                                              const int* __restrict__ batch,
                                              float* __restrict__ P, int M)
{
  gemm_body<K, RELU, HASBIAS, AF32, POOL>(Av, BhiT, BloT, bias, C, stats, batch, P, M,
                                          blockIdx.x, gridDim.x >> 1);
}

// ---- fused dispatch: blocks [0,g1blk) = K=128 POOL GEMM (h0 -> P1),
//      blocks [g1blk, g1blk+g2blk) = K=32 POOL GEMM (act -> P2). Independent
//      work; both ~90% idle solo -> overlap instead of serializing dispatches.
__global__ __launch_bounds__(256) void k_gemm2(const void* __restrict__ A1,
                                               const u16* __restrict__ B1hi,
                                               const u16* __restrict__ B1lo,
                                               const float* __restrict__ bias1,
                                               float* __restrict__ stats1,
                                               float* __restrict__ P1,
                                               const void* __restrict__ A2,
                                               const u16* __restrict__ B2hi,
                                               const u16* __restrict__ B2lo,
                                               const float* __restrict__ bias2,
                                               float* __restrict__ stats2,
                                               float* __restrict__ P2,
                                               const int* __restrict__ batch,
                                               int M, int g1blk, int g2blk)
{
  if ((int)blockIdx.x < g1blk)
    gemm_body<128, true, true, false, true>(A1, B1hi, B1lo, bias1, nullptr, stats1,
                                            batch, P1, M, blockIdx.x, g1blk >> 1);
  else
    gemm_body<32, true, true, true, true>(A2, B2hi, B2lo, bias2, nullptr, stats2,
                                          batch, P2, M, blockIdx.x - g1blk, g2blk >> 1);
}

// ---- prep0: blocks [0,NZ) zero scratch; [NZ,NZ+48) split Wg/W2 hi/lo T; rest: bounds ----
__global__ void k_prep0(const float* __restrict__ Wg, const float* __restrict__ W2,
                        u16* __restrict__ WghiT, u16* __restrict__ WgloT,
                        u16* __restrict__ W2hiT, u16* __restrict__ W2loT,
                        const int* __restrict__ batch, int* __restrict__ gofs,
                        int* __restrict__ zbase, int zwords, int NZ, int N, int B)
{
  const int bid = blockIdx.x, t = threadIdx.x;
  if (bid < NZ) {
    const int i = bid * 2048 + t * 8;       // zwords padded to multiple of 8
    if (i < zwords) {
      *(int4*)(zbase + i)     = make_int4(0, 0, 0, 0);
      *(int4*)(zbase + i + 4) = make_int4(0, 0, 0, 0);
    }
  } else if (bid < NZ + 48) {
    const int i = (bid - NZ) * 256 + t;
    if (i < 64 * 128) {
      int k = i >> 7, n = i & 127;
      float w = Wg[i]; u16 h = f2b(w);
      WghiT[n * 64 + k] = h; WgloT[n * 64 + k] = f2b(w - b2f(h));
    } else if (i < 64 * 128 + 32 * 128) {
      int j = i - 64 * 128;
      int k = j >> 7, n = j & 127;
      float w = W2[j]; u16 h = f2b(w);
      W2hiT[n * 32 + k] = h; W2loT[n * 32 + k] = f2b(w - b2f(h));
    }
  } else {
    const int i = (bid - NZ - 48) * 256 + t;
    if (i == 0) { for (int g = 0; g <= batch[0]; g++) gofs[g] = 0; }
    if (i == N - 1) { for (int g = batch[N - 1] + 1; g <= B; g++) gofs[g] = N; }
    if (i < N - 1) {
      const int b0 = batch[i], b1 = batch[i + 1];
      for (int g = b0 + 1; g <= b1; g++) gofs[g] = i + 1;
    }
  }
}

// ========== binned edge partition ==========
__global__ __launch_bounds__(256) void k_bincnt(const int* __restrict__ dst, int* __restrict__ btot,
                                                int E, int NB)
{
  extern __shared__ int hist[];
  const int tid = threadIdx.x;
  for (int i = tid; i < NB; i += 256) hist[i] = 0;
  __syncthreads();
  const int chunk = (E + gridDim.x - 1) / gridDim.x;
  const int start = blockIdx.x * chunk;
  const int end = min(start + chunk, E);
  for (int e = start + tid; e < end; e += 256) atomicAdd(&hist[((u32)dst[e]) >> BSHIFT], 1);
  __syncthreads();
  for (int i = tid; i < NB; i += 256) if (hist[i]) atomicAdd(&btot[i], hist[i]);
}

// single-block exclusive scan; out[0..n-1] = exclusive, out[n] = total
__global__ void k_exscan(const int* __restrict__ in, int* __restrict__ out, int n)
{
  __shared__ int s[256];
  const int t = threadIdx.x;
  const int per = (n + 255) / 256;
  const int base = t * per;
  int loc[8]; int sum = 0;
  for (int j = 0; j < per; j++) { int v = (base + j < n) ? in[base + j] : 0; loc[j] = sum; sum += v; }
  s[t] = sum; __syncthreads();
  for (int o = 1; o < 256; o <<= 1) {
    int x = (t >= o) ? s[t - o] : 0;
    __syncthreads();
    s[t] += x;
    __syncthreads();
  }
  const int ex = s[t] - sum;
  for (int j = 0; j < per; j++) if (base + j < n) out[base + j] = ex + loc[j];
  if (t == 255) out[n] = s[255];
}

// re-read edges, reserve per-(block,bucket) ranges, stream (dst,src) pairs
__global__ __launch_bounds__(256) void k_bin(const int* __restrict__ src, const int* __restrict__ dst,
                                             const int* __restrict__ bbase, int* __restrict__ bcur,
                                             uint2* __restrict__ pairs, int E, int NB)
{
  extern __shared__ int lds[];
  int* hist = lds; int* wbase = lds + NB;
  const int tid = threadIdx.x;
  for (int i = tid; i < NB; i += 256) hist[i] = 0;
  __syncthreads();
  const int chunk = (E + gridDim.x - 1) / gridDim.x;
  const int start = blockIdx.x * chunk;
  const int end = min(start + chunk, E);
  for (int e = start + tid; e < end; e += 256) atomicAdd(&hist[((u32)dst[e]) >> BSHIFT], 1);
  __syncthreads();
  for (int i = tid; i < NB; i += 256) {
    int c = hist[i];
    wbase[i] = c ? bbase[i] + atomicAdd(&bcur[i], c) : 0;
    hist[i] = 0;
  }
  __syncthreads();
  for (int e = start + tid; e < end; e += 256) {
    const int d = dst[e];
    const int b = ((u32)d) >> BSHIFT;
    const int o = atomicAdd(&hist[b], 1);
    pairs[wbase[b] + o] = make_uint2((u32)d, (u32)src[e]);
  }
}

// ---- per-bucket: degree hist -> LDS scan -> offsets/dinv/self-loop -> scatter ----
// Also fused: y[i] = bf16(x[i] * dinv[i]) for the bucket's own 512 nodes (coalesced).
__global__ __launch_bounds__(256) void k_bucket(const uint2* __restrict__ pairs,
                                                const int* __restrict__ bbase,
                                                const float* __restrict__ x,
                                                int* __restrict__ offsets, float* __restrict__ dinv,
                                                int* __restrict__ elist, u16* __restrict__ y,
                                                int N, int NB, int Etot)
{
  __shared__ int hist[512];
  __shared__ int scan[256];
  __shared__ int lcur[512];
  __shared__ float sdinv[512];
  const int b = blockIdx.x, t = threadIdx.x;
  const int nbase = b << BSHIFT;
  const int nn = min(1 << BSHIFT, N - nbase);
  hist[t] = 0; hist[256 + t] = 0;
  __syncthreads();
  const int p0 = bbase[b], p1 = bbase[b + 1];
  for (int p = p0 + t; p < p1; p += 256) atomicAdd(&hist[pairs[p].x - nbase], 1);
  __syncthreads();
  const int h0 = hist[2 * t], h1 = hist[2 * t + 1];
  const int psum = h0 + h1;
  scan[t] = psum; __syncthreads();
  for (int o = 1; o < 256; o <<= 1) {
    int xx = (t >= o) ? scan[t - o] : 0;
    __syncthreads();
    scan[t] += xx;
    __syncthreads();
  }
  const int ex = scan[t] - psum;   // edges in this bucket before node 2t
  const int li0 = 2 * t, li1 = 2 * t + 1;
  if (li0 < nn) {
    const int i = nbase + li0;
    const int off = p0 + ex + i;
    const float d = rsqrtf((float)(h0 + 1));
    offsets[i] = off; elist[off] = i; lcur[li0] = off + 1;
    dinv[i] = d; sdinv[li0] = d;
  }
  if (li1 < nn) {
    const int i = nbase + li1;
    const int off = p0 + ex + h0 + i;
    const float d = rsqrtf((float)(h1 + 1));
    offsets[i] = off; elist[off] = i; lcur[li1] = off + 1;
    dinv[i] = d; sdinv[li1] = d;
  }
  if (b == NB - 1 && t == 0) offsets[N] = Etot;
  __syncthreads();
  for (int p = p0 + t; p < p1; p += 256) {
    const uint2 pr = pairs[p];
    const int pos = atomicAdd(&lcur[pr.x - nbase], 1);
    elist[pos] = (int)pr.y;
  }
  // fused cast: y rows for this bucket (sdinv visible via the sync above)
  const size_t ebase = (size_t)nbase * 64;
  const int total = nn * 64;
  for (int i = t * 8; i < total; i += 256 * 8) {
    const float d = sdinv[i >> 6];
    f32x4 a = *(const f32x4*)(x + ebase + i);
    f32x4 c = *(const f32x4*)(x + ebase + i + 4);
    u16 o[8];
#pragma unroll
    for (int j = 0; j < 4; j++) { o[j] = f2b(a[j] * d); o[4 + j] = f2b(c[j] * d); }
    *(uint4*)(y + ebase + i) = *(uint4*)o;
  }
}

// ------- GCN aggregation: 2 nodes/wave (half-wave each), 4 groups x 8 lanes per node -------
// y premultiplied by dinv[src]; final scale by dinv[node]. ALL shfls wave-uniform
// (divergent __shfl on CDNA reads undefined data from EXEC-inactive lanes — r5/r6 bug).
__global__ __launch_bounds__(256) void k_agg(const u16* __restrict__ y, const int* __restrict__ offsets,
                                             const int* __restrict__ elist, const float* __restrict__ dinv,
                                             u16* __restrict__ aggx, int n)
{
  const int lane = threadIdx.x & 63;
  const int half = lane >> 5, l32 = lane & 31;
  const int g4 = l32 >> 3, sub = lane & 7;
  const int wid  = (blockIdx.x * 256 + threadIdx.x) >> 6;
  const int nw   = gridDim.x * 4;
  const int npair = (n + 1) >> 1;
  for (int pr = wid; pr < npair; pr += nw) {
    const int node = pr * 2 + half;          // n even -> node < n
    const int s0 = offsets[node], s1 = offsets[node + 1];
    const int mydeg = s1 - s0;
    const int degA = __shfl(mydeg, 0, 64);
    const int degB = __shfl(mydeg, 32, 64);
    const int degmax = max(degA, degB);
    float a[8];
#pragma unroll
    for (int t = 0; t < 8; t++) a[t] = 0.f;
    for (int base = 0; base < degmax; base += 32) {
      const int m = mydeg - base;            // may be <=0 for the finished half
      const int ev = (base + l32 < mydeg) ? elist[s0 + base + l32] : 0;
      const int iters = (min(32, degmax - base) + 3) >> 2;   // wave-uniform
      for (int it = 0; it < iters; it++) {
        const int j = it * 4 + g4;           // 0..31
        const int idx = __shfl(ev, half * 32 + j, 64);   // all lanes active
        if (j < m) {
          const uint4 v = *(const uint4*)(y + (size_t)idx * 64 + sub * 8);
          const u32 w[4] = {v.x, v.y, v.z, v.w};
#pragma unroll
          for (int t = 0; t < 4; t++) {
            a[2 * t]     += b2f((u16)w[t]);
            a[2 * t + 1] += b2f((u16)(w[t] >> 16));
          }
        }
      }
    }
#pragma unroll
    for (int t = 0; t < 8; t++) {
      a[t] += __shfl_xor(a[t], 8, 64);
      a[t] += __shfl_xor(a[t], 16, 64);
    }
    if (g4 == 0) {
      const float di = dinv[node];
      u16 o[8];
#pragma unroll
      for (int t = 0; t < 8; t++) o[t] = f2b(a[t] * di);
      *(uint4*)(aggx + (size_t)node * 64 + sub * 8) = *(uint4*)o;
    }
  }
}

// ---- fold BN0 into W1 (16 blocks x 8 k-rows): W1p = diag(a0)W1 hi/lo T, b1p = c0@W1+b1 ----
__global__ void k_prep1(const float* __restrict__ stats0, const float* __restrict__ W1,
                        const float* __restrict__ b1, const float* __restrict__ g0,
                        const float* __restrict__ be0, u16* __restrict__ W1hiT,
                        u16* __restrict__ W1loT, float* __restrict__ b1p, float n)
{
  __shared__ float A[8], Csh[8];
  const int t = threadIdx.x;  // 128 threads
  if (t < 8) {
    const int k = blockIdx.x * 8 + t;
    const float mu = stats0[k] / n;
    const float var = fmaxf(stats0[128 + k] / n - mu * mu, 0.f);
    const float a = g0[k] * rsqrtf(var + EPS);
    A[t] = a; Csh[t] = be0[k] - mu * a;
  }
  __syncthreads();
  float acc = (blockIdx.x == 0) ? b1[t] : 0.f;
#pragma unroll
  for (int kk = 0; kk < 8; kk++) {
    const int k = blockIdx.x * 8 + kk;
    const float w0 = W1[k * 128 + t];
    acc += Csh[kk] * w0;
    const float w = A[kk] * w0;
    const u16 h = f2b(w);
    W1hiT[t * 128 + k] = h;
    W1loT[t * 128 + k] = f2b(w - b2f(h));
  }
  atomicAdd(&b1p[t], acc);
}

// ---- merged BN1/BN2+W3 fold + per-graph head (was k_prep2 + k_out2; each block
//      redundantly computes the 256-wide fold — trivial vs a dispatch gap) ----
__global__ void k_out3(const float* __restrict__ P1, const float* __restrict__ P2,
                       const int* __restrict__ gofs,
                       const float* __restrict__ stats1, const float* __restrict__ stats2,
                       const float* __restrict__ g1, const float* __restrict__ be1,
                       const float* __restrict__ g2, const float* __restrict__ be2,
                       const float* __restrict__ W3, const float* __restrict__ b3,
                       float* __restrict__ out, int B, float n)
{
  __shared__ float w1s[128], w2s[128], red[256], cS[2];
  const int t = threadIdx.x;  // 256 threads
  float c, wv;
  if (t < 128) {
    const float mu = stats1[t] / n;
    const float var = fmaxf(stats1[128 + t] / n - mu * mu, 0.f);
    const float a = g1[t] * rsqrtf(var + EPS);
    c = be1[t] - mu * a;
    wv = W3[t];
    w1s[t] = a * wv;
  } else {
    const int f = t - 128;
    const float mu = stats2[f] / n;
    const float var = fmaxf(stats2[128 + f] / n - mu * mu, 0.f);
    const float a = g2[f] * rsqrtf(var + EPS);
    c = be2[f] - mu * a;
    wv = W3[t];
    w2s[f] = a * wv;
  }
  red[t] = c * wv; __syncthreads();
  for (int o = 128; o; o >>= 1) { if (t < o) red[t] += red[t + o]; __syncthreads(); }
  if (t == 0) { cS[0] = red[0] + b3[0]; cS[1] = b3[0]; }
  __syncthreads();
  const int lane = t & 63;
  const int g = (blockIdx.x * 256 + t) >> 6;
  if (g >= B) return;
  const int cnt = gofs[g + 1] - gofs[g];
  const int k = 2 * lane;
  float d = P1[g * 128 + k] * w1s[k] + P1[g * 128 + k + 1] * w1s[k + 1]
          + P2[g * 128 + k] * w2s[k] + P2[g * 128 + k + 1] * w2s[k + 1];
#pragma unroll
  for (int o = 1; o < 64; o <<= 1) d += __shfl_xor(d, o, 64);
  if (lane == 0) out[g] = (cnt > 0) ? d / (float)cnt + cS[0] : cS[1];
}

extern "C" void kernel_launch(void* const* d_in, const int* in_sizes, int n_in,
                              void* d_out, int out_size, void* d_ws, size_t ws_size,
                              hipStream_t stream)
{
  const float* x    = (const float*)d_in[0];
  const float* act  = (const float*)d_in[1];
  const float* Wg   = (const float*)d_in[2];
  const float* bg   = (const float*)d_in[3];
  const float* g0   = (const float*)d_in[4];
  const float* be0  = (const float*)d_in[5];
  const float* W1   = (const float*)d_in[6];
  const float* b1   = (const float*)d_in[7];
  const float* g1   = (const float*)d_in[8];
  const float* be1  = (const float*)d_in[9];
  const float* W2   = (const float*)d_in[10];
  const float* b2   = (const float*)d_in[11];
  const float* g2   = (const float*)d_in[12];
  const float* be2  = (const float*)d_in[13];
  const float* W3   = (const float*)d_in[14];
  const float* b3   = (const float*)d_in[15];
  const int* eidx   = (const int*)d_in[16];
  const int* batch  = (const int*)d_in[17];

  const int N = in_sizes[17];          // 200000
  const int E = in_sizes[16] / 2;      // 1600000
  const int B = out_size;              // 1000
  const int* src = eidx;
  const int* dst = eidx + E;
  const int NB = (N + (1 << BSHIFT) - 1) >> BSHIFT;   // ~391 buckets

  char* ws = (char*)d_ws;
  size_t off = 0;
  auto alloc = [&](size_t bytes) -> char* {
    off = (off + 255) & ~(size_t)255;
    char* p = ws + off; off += bytes; return p;
  };

  u16* bufA = (u16*)alloc((size_t)N * 128 * 2);   // h0 (h1/h2 never materialized)
  u16* xb   = (u16*)alloc((size_t)N * 64 * 2);    // y (premult bf16 x)
  u16* aggx = (u16*)alloc((size_t)N * 64 * 2);

  int zwords = 768 + 128 + 2 * NB + 2 * 128 * B;  // stats+b1p+bins + P1+P2
  zwords = (zwords + 7) & ~7;                     // pad for int4-pair zeroing
  char* zbase   = alloc((size_t)zwords * 4);
  float* stats0 = (float*)zbase;
  float* stats1 = stats0 + 256;
  float* stats2 = stats1 + 256;
  float* b1p    = stats2 + 256;
  int*   btot   = (int*)(b1p + 128);
  int*   bcur   = btot + NB;
  float* P1     = (float*)(bcur + NB);            // [B,128] graph sums of h1
  float* P2     = P1 + 128 * B;                   // [B,128] graph sums of h2

  int*   offsets = (int*)alloc((size_t)(N + 1) * 4);
  float* dinv    = (float*)alloc((size_t)N * 4);
  int*   elist   = (int*)alloc((size_t)(E + N) * 4);
  uint2* pairs   = (uint2*)alloc((size_t)E * 8);
  int*   bbase   = (int*)alloc((size_t)(NB + 1) * 4);
  int*   gofs    = (int*)alloc((size_t)(B + 1) * 4);
  u16*   WghiT   = (u16*)alloc(128 * 64 * 2);
  u16*   WgloT   = (u16*)alloc(128 * 64 * 2);
  u16*   W1hiT   = (u16*)alloc(128 * 128 * 2);
  u16*   W1loT   = (u16*)alloc(128 * 128 * 2);
  u16*   W2hiT   = (u16*)alloc(128 * 32 * 2);
  u16*   W2loT   = (u16*)alloc(128 * 32 * 2);

  u16* h0 = bufA;

  // dynamic-LDS sizes for the gemm bodies: 2*64*K u16 *2(hi/lo) + 2*64 f32
  const int smem64  = 2 * 64 * 64 * 2 + 512;      // 16896 B
  const int smem128 = 2 * 64 * 128 * 2 + 512;     // 33280 B (max in fused)

  // prep0: zero scratch (parallel, ~1 MB) + weight split + graph bounds
  const int NZ = (zwords + 2047) / 2048;          // 256 thr x 8 words per block
  const int nbounds = (N + 255) / 256;
  k_prep0<<<NZ + 48 + nbounds, 256, 0, stream>>>(Wg, W2, WghiT, WgloT, W2hiT, W2loT,
                                                 batch, gofs, (int*)zbase, zwords, NZ, N, B);
  // binned edge partition -> per-bucket CSR build + fused x->y cast
  k_bincnt<<<256, 256, NB * 4, stream>>>(dst, btot, E, NB);
  k_exscan<<<1, 256, 0, stream>>>(btot, bbase, NB);
  k_bin<<<256, 256, 2 * NB * 4, stream>>>(src, dst, bbase, bcur, pairs, E, NB);
  k_bucket<<<NB, 256, 0, stream>>>(pairs, bbase, x, offsets, dinv, elist, xb, N, NB, E + N);
  // aggregate, GEMM (+stats0) -> h0
  k_agg<<<2048, 256, 0, stream>>>(xb, offsets, elist, dinv, aggx, N);
  k_gemm<64, true, true, false, false><<<768, 256, smem64, stream>>>(aggx, WghiT, WgloT, bg,
                                                                     h0, stats0, nullptr, nullptr, N);
  // fold BN0 into W1
  k_prep1<<<16, 128, 0, stream>>>(stats0, W1, b1, g0, be0, W1hiT, W1loT, b1p, (float)N);
  // FUSED: h1-GEMM (K=128, h0 -> P1) overlapped with h2-GEMM (K=32, act -> P2)
  k_gemm2<<<768 + 512, 256, smem128, stream>>>(h0, W1hiT, W1loT, b1p, stats1, P1,
                                               act, W2hiT, W2loT, b2, stats2, P2,
                                               batch, N, 768, 512);
  // merged BN1/BN2+W3 fold + per-graph head
  k_out3<<<(B * 64 + 255) / 256, 256, 0, stream>>>(P1, P2, gofs, stats1, stats2,
                                                   g1, be1, g2, be2, W3, b3,
                                                   (float*)d_out, B, (float)N);
}

// Round 11
// 362.265 us; speedup vs baseline: 1.1061x; 1.0270x over previous
//
#include <hip/hip_runtime.h>

typedef unsigned short u16;
typedef unsigned int   u32;
typedef __bf16 bf16x8 __attribute__((ext_vector_type(8)));
typedef float  f32x4  __attribute__((ext_vector_type(4)));

#define EPS 1e-5f
#define BSHIFT 9               // 512 node ids per bucket

__device__ __forceinline__ float b2f(u16 u){ union{u32 i; float f;} v; v.i=((u32)u)<<16; return v.f; }
__device__ __forceinline__ u16 f2b(float f){
  u32 x = __float_as_uint(f);
  u32 r = x + 0x7fffu + ((x>>16)&1u);   // round-to-nearest-even
  return (u16)(r>>16);
}

// ---- GEMM body: C[M,128] = act(A[M,K] @ (Bhi+Blo) + bias), fused BN stats ----
// v11: every GEMM config so far lands at ~1.05 TB/s with all pipes idle — theory:
// the POOL epilogue's global atomicAdds count in vmcnt, so each tile's A-load
// s_waitcnt vmcnt(0) also drains ~134 queued atomic round-trips (r7's "atomics
// don't matter" was confounded by its VGPR cliff). Fix: POOL path accumulates P
// in LDS (ds_add_f32, not vmcnt-counted) + caches batch[] in LDS once per block
// -> A-loads are the ONLY per-tile vmem. Requires contiguous (bijective) tile
// ranges so a block's graphs form one window (GCAP=8, rare overflow falls back
// to direct atomic). gemm64 (non-POOL, strided) untouched as control.
// Ledger: forced launch_bounds -> spill (r2/r4); occupancy up -> slower (r8).
template<int K, bool RELU, bool HASBIAS, bool AF32, bool POOL>
__device__ __forceinline__ void gemm_body(const void* __restrict__ Av,
                                          const u16* __restrict__ BhiT,
                                          const u16* __restrict__ BloT,
                                          const float* __restrict__ bias,
                                          u16* __restrict__ C,
                                          float* __restrict__ stats,
                                          const int* __restrict__ batch,
                                          float* __restrict__ P, int M,
                                          int bid, int halfg)
{
  constexpr int KM = K / 8;                 // 8-elem (16B) blocks per row
  constexpr int KR = K / 32;                // bf16x8 fragments per lane
  constexpr int GCAP = 8;                   // LDS graph-window capacity
  extern __shared__ char smem[];
  u16* lds    = (u16*)smem;                 // [hi|lo][64 cols][K swizzled]
  float* sred = (float*)(smem + (size_t)2 * 64 * K * 2);
  float* qred = sred + 64;
  u16*  sbatch = (u16*)(qred + 64);         // [1024] block's batch slice (POOL)
  float* Pacc  = (float*)(sbatch + 1024);   // [GCAP*64] LDS P window (POOL)
  const int tid = threadIdx.x;
  const int ch = (bid >= halfg) ? 1 : 0;    // column half: cols ch*64..+63
  const int t0 = bid - ch * halfg;          // pair (b, b+halfg): same XCD
  for (int i = tid; i < 64 * KM; i += 256) {
    const int n = i / KM, kb = i % KM;
    const int kb2 = kb ^ (n & (KM - 1));
    const int gsrc = ((ch * 64 + n) * KM + kb) * 8;
    *(uint4*)(&lds[(n * KM + kb2) * 8])          = *(const uint4*)(BhiT + gsrc);
    *(uint4*)(&lds[64 * K + (n * KM + kb2) * 8]) = *(const uint4*)(BloT + gsrc);
  }
  if (tid < 64) { sred[tid] = 0.f; qred[tid] = 0.f; }
  const int nmt = (M + 127) >> 7;           // 128-row macro tiles (M % 64 == 0)
  // POOL: contiguous bijective tile range; non-POOL: strided walk (control)
  int mt_begin, mt_end, mt_step, rlo = 0;
  if (POOL) {
    const int qt = nmt / halfg, rm = nmt % halfg;
    mt_begin = (t0 < rm) ? t0 * (qt + 1) : rm * (qt + 1) + (t0 - rm) * qt;
    mt_end   = mt_begin + ((t0 < rm) ? qt + 1 : qt);
    mt_step  = 1;
    rlo = mt_begin << 7;
    const int rcnt = min(mt_end << 7, M) - rlo;   // <= 1024 (max 7 tiles/block)
    for (int i = tid; i < rcnt; i += 256) sbatch[i] = (u16)batch[rlo + i];
    for (int i = tid; i < GCAP * 64; i += 256) Pacc[i] = 0.f;
  } else {
    mt_begin = t0; mt_end = nmt; mt_step = halfg;
  }
  __syncthreads();
  const int g_lo = POOL ? (int)sbatch[0] : 0;     // wave-uniform broadcast read
  const int wid = tid >> 6, lane = tid & 63, q = lane >> 4, r16 = lane & 15;
  float ls[4], lq[4];
#pragma unroll
  for (int nb = 0; nb < 4; nb++) { ls[nb] = 0.f; lq[nb] = 0.f; }
  float bv[4];
#pragma unroll
  for (int nb = 0; nb < 4; nb++) bv[nb] = HASBIAS ? bias[ch * 64 + nb * 16 + r16] : 0.f;

  for (int mt = mt_begin; mt < mt_end; mt += mt_step) {
    const int row0 = mt << 7;               // rt=0 rows always valid
    const bool ok1 = (row0 + 64) < M;       // rt=1 rows row0+64..127

    bf16x8 av[2][KR];
    if (AF32) {
      const float* Af = (const float*)Av + (size_t)(row0 + (wid << 4) + r16) * K + q * 8;
#pragma unroll
      for (int kk = 0; kk < KR; kk++) {
        f32x4 x0 = *(const f32x4*)(Af + kk * 32);
        f32x4 x1 = *(const f32x4*)(Af + kk * 32 + 4);
#pragma unroll
        for (int j = 0; j < 4; j++) { av[0][kk][j] = (__bf16)x0[j]; av[0][kk][4 + j] = (__bf16)x1[j]; }
      }
      if (ok1) {
        const float* Ag = Af + (size_t)64 * K;
#pragma unroll
        for (int kk = 0; kk < KR; kk++) {
          f32x4 x0 = *(const f32x4*)(Ag + kk * 32);
          f32x4 x1 = *(const f32x4*)(Ag + kk * 32 + 4);
#pragma unroll
          for (int j = 0; j < 4; j++) { av[1][kk][j] = (__bf16)x0[j]; av[1][kk][4 + j] = (__bf16)x1[j]; }
        }
      }
    } else {
      const u16* Ab = (const u16*)Av + (size_t)(row0 + (wid << 4) + r16) * K + q * 8;
#pragma unroll
      for (int kk = 0; kk < KR; kk++) av[0][kk] = *(const bf16x8*)(Ab + kk * 32);
      if (ok1) {
#pragma unroll
        for (int kk = 0; kk < KR; kk++) av[1][kk] = *(const bf16x8*)(Ab + (size_t)64 * K + kk * 32);
      }
    }

    f32x4 acc[2][4];
#pragma unroll
    for (int rt = 0; rt < 2; rt++)
#pragma unroll
      for (int nb = 0; nb < 4; nb++) acc[rt][nb] = (f32x4){0.f, 0.f, 0.f, 0.f};
#pragma unroll
    for (int kk = 0; kk < KR; kk++) {
#pragma unroll
      for (int nb = 0; nb < 4; nb++) {
        const int n = nb * 16 + r16;
        const int kb2 = (kk * 4 + q) ^ (n & (KM - 1));
        const bf16x8 bh = *(const bf16x8*)(&lds[(n * KM + kb2) * 8]);
        const bf16x8 bl = *(const bf16x8*)(&lds[64 * K + (n * KM + kb2) * 8]);
        acc[0][nb] = __builtin_amdgcn_mfma_f32_16x16x32_bf16(av[0][kk], bh, acc[0][nb], 0, 0, 0);
        acc[0][nb] = __builtin_amdgcn_mfma_f32_16x16x32_bf16(av[0][kk], bl, acc[0][nb], 0, 0, 0);
        if (ok1) {
          acc[1][nb] = __builtin_amdgcn_mfma_f32_16x16x32_bf16(av[1][kk], bh, acc[1][nb], 0, 0, 0);
          acc[1][nb] = __builtin_amdgcn_mfma_f32_16x16x32_bf16(av[1][kk], bl, acc[1][nb], 0, 0, 0);
        }
      }
    }

#pragma unroll
    for (int rt = 0; rt < 2; rt++) {
      if (rt && !ok1) continue;
      const int rbase = row0 + rt * 64 + (wid << 4) + (q << 2);
#pragma unroll
      for (int nb = 0; nb < 4; nb++) {
        const int col = ch * 64 + nb * 16 + r16;
#pragma unroll
        for (int r = 0; r < 4; r++) {
          float v = acc[rt][nb][r] + bv[nb];
          if (RELU) v = fmaxf(v, 0.f);
          ls[nb] += v; lq[nb] += v * v;
          if (!POOL) C[(size_t)(rbase + r) * 128 + col] = f2b(v);
          else acc[rt][nb][r] = v;
        }
      }
      if (POOL) {
        int bg[4];
#pragma unroll
        for (int r = 0; r < 4; r++) bg[r] = (int)sbatch[rbase - rlo + r];   // LDS, no vmcnt
        const int g0 = __shfl(bg[0], 0, 64);    // batch[first row of wave tile]
        const int g1 = __shfl(bg[3], 48, 64);   // batch[last row of wave tile]
        for (int g = g0; g <= g1; ++g) {        // wave-uniform, almost always 1 iter
#pragma unroll
          for (int nb = 0; nb < 4; nb++) {
            float sv = 0.f;
#pragma unroll
            for (int r = 0; r < 4; r++) sv += (bg[r] == g) ? acc[rt][nb][r] : 0.f;
            sv += __shfl_xor(sv, 16, 64);       // sum the 4 q-groups (16 rows)
            sv += __shfl_xor(sv, 32, 64);
            if (q == 0) {
              const int gi = g - g_lo;          // wave-uniform branch
              if ((unsigned)gi < GCAP) atomicAdd(&Pacc[gi * 64 + nb * 16 + r16], sv);
              else atomicAdd(&P[g * 128 + ch * 64 + nb * 16 + r16], sv);
            }
          }
        }
      }
    }
  }
#pragma unroll
  for (int nb = 0; nb < 4; nb++) {
    atomicAdd(&sred[nb * 16 + r16], ls[nb]);
    atomicAdd(&qred[nb * 16 + r16], lq[nb]);
  }
  __syncthreads();
  if (tid < 64) {
    atomicAdd(&stats[ch * 64 + tid], sred[tid]);
    atomicAdd(&stats[128 + ch * 64 + tid], qred[tid]);
  }
  if (POOL) {
    // one flush per block; zero entries skipped (RELU values are nonneg, so a
    // zero sum means zero contribution — skipping is exact)
    for (int i = tid; i < GCAP * 64; i += 256) {
      const float v = Pacc[i];
      if (v != 0.f) atomicAdd(&P[(g_lo + (i >> 6)) * 128 + ch * 64 + (i & 63)], v);
    }
  }
}

template<int K, bool RELU, bool HASBIAS, bool AF32, bool POOL>
__global__ __launch_bounds__(256) void k_gemm(const void* __restrict__ Av,
                                              const u16* __restrict__ BhiT,
                                              const u16* __restrict__ BloT,
                                              const float* __restrict__ bias,
                                              u16* __restrict__ C,
                                              float* __restrict__ stats,
                                              const int* __restrict__ batch,
                                              float* __restrict__ P, int M)
{
  gemm_body<K, RELU, HASBIAS, AF32, POOL>(Av, BhiT, BloT, bias, C, stats, batch, P, M,
                                          blockIdx.x, gridDim.x >> 1);
}

// ---- fused dispatch: blocks [0,g1blk) = K=128 POOL GEMM (h0 -> P1),
//      blocks [g1blk, g1blk+g2blk) = K=32 POOL GEMM (act -> P2). Independent
//      work; both ~90% idle solo -> overlap instead of serializing dispatches.
__global__ __launch_bounds__(256) void k_gemm2(const void* __restrict__ A1,
                                               const u16* __restrict__ B1hi,
                                               const u16* __restrict__ B1lo,
                                               const float* __restrict__ bias1,
                                               float* __restrict__ stats1,
                                               float* __restrict__ P1,
                                               const void* __restrict__ A2,
                                               const u16* __restrict__ B2hi,
                                               const u16* __restrict__ B2lo,
                                               const float* __restrict__ bias2,
                                               float* __restrict__ stats2,
                                               float* __restrict__ P2,
                                               const int* __restrict__ batch,
                                               int M, int g1blk, int g2blk)
{
  if ((int)blockIdx.x < g1blk)
    gemm_body<128, true, true, false, true>(A1, B1hi, B1lo, bias1, nullptr, stats1,
                                            batch, P1, M, blockIdx.x, g1blk >> 1);
  else
    gemm_body<32, true, true, true, true>(A2, B2hi, B2lo, bias2, nullptr, stats2,
                                          batch, P2, M, blockIdx.x - g1blk, g2blk >> 1);
}

// ---- prep0: blocks [0,NZ) zero scratch; [NZ,NZ+48) split Wg/W2 hi/lo T; rest: bounds ----
__global__ void k_prep0(const float* __restrict__ Wg, const float* __restrict__ W2,
                        u16* __restrict__ WghiT, u16* __restrict__ WgloT,
                        u16* __restrict__ W2hiT, u16* __restrict__ W2loT,
                        const int* __restrict__ batch, int* __restrict__ gofs,
                        int* __restrict__ zbase, int zwords, int NZ, int N, int B)
{
  const int bid = blockIdx.x, t = threadIdx.x;
  if (bid < NZ) {
    const int i = bid * 2048 + t * 8;       // zwords padded to multiple of 8
    if (i < zwords) {
      *(int4*)(zbase + i)     = make_int4(0, 0, 0, 0);
      *(int4*)(zbase + i + 4) = make_int4(0, 0, 0, 0);
    }
  } else if (bid < NZ + 48) {
    const int i = (bid - NZ) * 256 + t;
    if (i < 64 * 128) {
      int k = i >> 7, n = i & 127;
      float w = Wg[i]; u16 h = f2b(w);
      WghiT[n * 64 + k] = h; WgloT[n * 64 + k] = f2b(w - b2f(h));
    } else if (i < 64 * 128 + 32 * 128) {
      int j = i - 64 * 128;
      int k = j >> 7, n = j & 127;
      float w = W2[j]; u16 h = f2b(w);
      W2hiT[n * 32 + k] = h; W2loT[n * 32 + k] = f2b(w - b2f(h));
    }
  } else {
    const int i = (bid - NZ - 48) * 256 + t;
    if (i == 0) { for (int g = 0; g <= batch[0]; g++) gofs[g] = 0; }
    if (i == N - 1) { for (int g = batch[N - 1] + 1; g <= B; g++) gofs[g] = N; }
    if (i < N - 1) {
      const int b0 = batch[i], b1 = batch[i + 1];
      for (int g = b0 + 1; g <= b1; g++) gofs[g] = i + 1;
    }
  }
}

// ========== binned edge partition ==========
__global__ __launch_bounds__(256) void k_bincnt(const int* __restrict__ dst, int* __restrict__ btot,
                                                int E, int NB)
{
  extern __shared__ int hist[];
  const int tid = threadIdx.x;
  for (int i = tid; i < NB; i += 256) hist[i] = 0;
  __syncthreads();
  const int chunk = (E + gridDim.x - 1) / gridDim.x;
  const int start = blockIdx.x * chunk;
  const int end = min(start + chunk, E);
  for (int e = start + tid; e < end; e += 256) atomicAdd(&hist[((u32)dst[e]) >> BSHIFT], 1);
  __syncthreads();
  for (int i = tid; i < NB; i += 256) if (hist[i]) atomicAdd(&btot[i], hist[i]);
}

// single-block exclusive scan; out[0..n-1] = exclusive, out[n] = total
__global__ void k_exscan(const int* __restrict__ in, int* __restrict__ out, int n)
{
  __shared__ int s[256];
  const int t = threadIdx.x;
  const int per = (n + 255) / 256;
  const int base = t * per;
  int loc[8]; int sum = 0;
  for (int j = 0; j < per; j++) { int v = (base + j < n) ? in[base + j] : 0; loc[j] = sum; sum += v; }
  s[t] = sum; __syncthreads();
  for (int o = 1; o < 256; o <<= 1) {
    int x = (t >= o) ? s[t - o] : 0;
    __syncthreads();
    s[t] += x;
    __syncthreads();
  }
  const int ex = s[t] - sum;
  for (int j = 0; j < per; j++) if (base + j < n) out[base + j] = ex + loc[j];
  if (t == 255) out[n] = s[255];
}

// re-read edges, reserve per-(block,bucket) ranges, stream (dst,src) pairs
__global__ __launch_bounds__(256) void k_bin(const int* __restrict__ src, const int* __restrict__ dst,
                                             const int* __restrict__ bbase, int* __restrict__ bcur,
                                             uint2* __restrict__ pairs, int E, int NB)
{
  extern __shared__ int lds[];
  int* hist = lds; int* wbase = lds + NB;
  const int tid = threadIdx.x;
  for (int i = tid; i < NB; i += 256) hist[i] = 0;
  __syncthreads();
  const int chunk = (E + gridDim.x - 1) / gridDim.x;
  const int start = blockIdx.x * chunk;
  const int end = min(start + chunk, E);
  for (int e = start + tid; e < end; e += 256) atomicAdd(&hist[((u32)dst[e]) >> BSHIFT], 1);
  __syncthreads();
  for (int i = tid; i < NB; i += 256) {
    int c = hist[i];
    wbase[i] = c ? bbase[i] + atomicAdd(&bcur[i], c) : 0;
    hist[i] = 0;
  }
  __syncthreads();
  for (int e = start + tid; e < end; e += 256) {
    const int d = dst[e];
    const int b = ((u32)d) >> BSHIFT;
    const int o = atomicAdd(&hist[b], 1);
    pairs[wbase[b] + o] = make_uint2((u32)d, (u32)src[e]);
  }
}

// ---- per-bucket: degree hist -> LDS scan -> offsets/dinv/self-loop -> scatter ----
// Also fused: y[i] = bf16(x[i] * dinv[i]) for the bucket's own 512 nodes (coalesced).
__global__ __launch_bounds__(256) void k_bucket(const uint2* __restrict__ pairs,
                                                const int* __restrict__ bbase,
                                                const float* __restrict__ x,
                                                int* __restrict__ offsets, float* __restrict__ dinv,
                                                int* __restrict__ elist, u16* __restrict__ y,
                                                int N, int NB, int Etot)
{
  __shared__ int hist[512];
  __shared__ int scan[256];
  __shared__ int lcur[512];
  __shared__ float sdinv[512];
  const int b = blockIdx.x, t = threadIdx.x;
  const int nbase = b << BSHIFT;
  const int nn = min(1 << BSHIFT, N - nbase);
  hist[t] = 0; hist[256 + t] = 0;
  __syncthreads();
  const int p0 = bbase[b], p1 = bbase[b + 1];
  for (int p = p0 + t; p < p1; p += 256) atomicAdd(&hist[pairs[p].x - nbase], 1);
  __syncthreads();
  const int h0 = hist[2 * t], h1 = hist[2 * t + 1];
  const int psum = h0 + h1;
  scan[t] = psum; __syncthreads();
  for (int o = 1; o < 256; o <<= 1) {
    int xx = (t >= o) ? scan[t - o] : 0;
    __syncthreads();
    scan[t] += xx;
    __syncthreads();
  }
  const int ex = scan[t] - psum;   // edges in this bucket before node 2t
  const int li0 = 2 * t, li1 = 2 * t + 1;
  if (li0 < nn) {
    const int i = nbase + li0;
    const int off = p0 + ex + i;
    const float d = rsqrtf((float)(h0 + 1));
    offsets[i] = off; elist[off] = i; lcur[li0] = off + 1;
    dinv[i] = d; sdinv[li0] = d;
  }
  if (li1 < nn) {
    const int i = nbase + li1;
    const int off = p0 + ex + h0 + i;
    const float d = rsqrtf((float)(h1 + 1));
    offsets[i] = off; elist[off] = i; lcur[li1] = off + 1;
    dinv[i] = d; sdinv[li1] = d;
  }
  if (b == NB - 1 && t == 0) offsets[N] = Etot;
  __syncthreads();
  for (int p = p0 + t; p < p1; p += 256) {
    const uint2 pr = pairs[p];
    const int pos = atomicAdd(&lcur[pr.x - nbase], 1);
    elist[pos] = (int)pr.y;
  }
  // fused cast: y rows for this bucket (sdinv visible via the sync above)
  const size_t ebase = (size_t)nbase * 64;
  const int total = nn * 64;
  for (int i = t * 8; i < total; i += 256 * 8) {
    const float d = sdinv[i >> 6];
    f32x4 a = *(const f32x4*)(x + ebase + i);
    f32x4 c = *(const f32x4*)(x + ebase + i + 4);
    u16 o[8];
#pragma unroll
    for (int j = 0; j < 4; j++) { o[j] = f2b(a[j] * d); o[4 + j] = f2b(c[j] * d); }
    *(uint4*)(y + ebase + i) = *(uint4*)o;
  }
}

// ------- GCN aggregation: 2 nodes/wave (half-wave each), 4 groups x 8 lanes per node -------
// y premultiplied by dinv[src]; final scale by dinv[node]. ALL shfls wave-uniform
// (divergent __shfl on CDNA reads undefined data from EXEC-inactive lanes — r5/r6 bug).
__global__ __launch_bounds__(256) void k_agg(const u16* __restrict__ y, const int* __restrict__ offsets,
                                             const int* __restrict__ elist, const float* __restrict__ dinv,
                                             u16* __restrict__ aggx, int n)
{
  const int lane = threadIdx.x & 63;
  const int half = lane >> 5, l32 = lane & 31;
  const int g4 = l32 >> 3, sub = lane & 7;
  const int wid  = (blockIdx.x * 256 + threadIdx.x) >> 6;
  const int nw   = gridDim.x * 4;
  const int npair = (n + 1) >> 1;
  for (int pr = wid; pr < npair; pr += nw) {
    const int node = pr * 2 + half;          // n even -> node < n
    const int s0 = offsets[node], s1 = offsets[node + 1];
    const int mydeg = s1 - s0;
    const int degA = __shfl(mydeg, 0, 64);
    const int degB = __shfl(mydeg, 32, 64);
    const int degmax = max(degA, degB);
    float a[8];
#pragma unroll
    for (int t = 0; t < 8; t++) a[t] = 0.f;
    for (int base = 0; base < degmax; base += 32) {
      const int m = mydeg - base;            // may be <=0 for the finished half
      const int ev = (base + l32 < mydeg) ? elist[s0 + base + l32] : 0;
      const int iters = (min(32, degmax - base) + 3) >> 2;   // wave-uniform
      for (int it = 0; it < iters; it++) {
        const int j = it * 4 + g4;           // 0..31
        const int idx = __shfl(ev, half * 32 + j, 64);   // all lanes active
        if (j < m) {
          const uint4 v = *(const uint4*)(y + (size_t)idx * 64 + sub * 8);
          const u32 w[4] = {v.x, v.y, v.z, v.w};
#pragma unroll
          for (int t = 0; t < 4; t++) {
            a[2 * t]     += b2f((u16)w[t]);
            a[2 * t + 1] += b2f((u16)(w[t] >> 16));
          }
        }
      }
    }
#pragma unroll
    for (int t = 0; t < 8; t++) {
      a[t] += __shfl_xor(a[t], 8, 64);
      a[t] += __shfl_xor(a[t], 16, 64);
    }
    if (g4 == 0) {
      const float di = dinv[node];
      u16 o[8];
#pragma unroll
      for (int t = 0; t < 8; t++) o[t] = f2b(a[t] * di);
      *(uint4*)(aggx + (size_t)node * 64 + sub * 8) = *(uint4*)o;
    }
  }
}

// ---- fold BN0 into W1 (16 blocks x 8 k-rows): W1p = diag(a0)W1 hi/lo T, b1p = c0@W1+b1 ----
__global__ void k_prep1(const float* __restrict__ stats0, const float* __restrict__ W1,
                        const float* __restrict__ b1, const float* __restrict__ g0,
                        const float* __restrict__ be0, u16* __restrict__ W1hiT,
                        u16* __restrict__ W1loT, float* __restrict__ b1p, float n)
{
  __shared__ float A[8], Csh[8];
  const int t = threadIdx.x;  // 128 threads
  if (t < 8) {
    const int k = blockIdx.x * 8 + t;
    const float mu = stats0[k] / n;
    const float var = fmaxf(stats0[128 + k] / n - mu * mu, 0.f);
    const float a = g0[k] * rsqrtf(var + EPS);
    A[t] = a; Csh[t] = be0[k] - mu * a;
  }
  __syncthreads();
  float acc = (blockIdx.x == 0) ? b1[t] : 0.f;
#pragma unroll
  for (int kk = 0; kk < 8; kk++) {
    const int k = blockIdx.x * 8 + kk;
    const float w0 = W1[k * 128 + t];
    acc += Csh[kk] * w0;
    const float w = A[kk] * w0;
    const u16 h = f2b(w);
    W1hiT[t * 128 + k] = h;
    W1loT[t * 128 + k] = f2b(w - b2f(h));
  }
  atomicAdd(&b1p[t], acc);
}

// ---- merged BN1/BN2+W3 fold + per-graph head (was k_prep2 + k_out2; each block
//      redundantly computes the 256-wide fold — trivial vs a dispatch gap) ----
__global__ void k_out3(const float* __restrict__ P1, const float* __restrict__ P2,
                       const int* __restrict__ gofs,
                       const float* __restrict__ stats1, const float* __restrict__ stats2,
                       const float* __restrict__ g1, const float* __restrict__ be1,
                       const float* __restrict__ g2, const float* __restrict__ be2,
                       const float* __restrict__ W3, const float* __restrict__ b3,
                       float* __restrict__ out, int B, float n)
{
  __shared__ float w1s[128], w2s[128], red[256], cS[2];
  const int t = threadIdx.x;  // 256 threads
  float c, wv;
  if (t < 128) {
    const float mu = stats1[t] / n;
    const float var = fmaxf(stats1[128 + t] / n - mu * mu, 0.f);
    const float a = g1[t] * rsqrtf(var + EPS);
    c = be1[t] - mu * a;
    wv = W3[t];
    w1s[t] = a * wv;
  } else {
    const int f = t - 128;
    const float mu = stats2[f] / n;
    const float var = fmaxf(stats2[128 + f] / n - mu * mu, 0.f);
    const float a = g2[f] * rsqrtf(var + EPS);
    c = be2[f] - mu * a;
    wv = W3[t];
    w2s[f] = a * wv;
  }
  red[t] = c * wv; __syncthreads();
  for (int o = 128; o; o >>= 1) { if (t < o) red[t] += red[t + o]; __syncthreads(); }
  if (t == 0) { cS[0] = red[0] + b3[0]; cS[1] = b3[0]; }
  __syncthreads();
  const int lane = t & 63;
  const int g = (blockIdx.x * 256 + t) >> 6;
  if (g >= B) return;
  const int cnt = gofs[g + 1] - gofs[g];
  const int k = 2 * lane;
  float d = P1[g * 128 + k] * w1s[k] + P1[g * 128 + k + 1] * w1s[k + 1]
          + P2[g * 128 + k] * w2s[k] + P2[g * 128 + k + 1] * w2s[k + 1];
#pragma unroll
  for (int o = 1; o < 64; o <<= 1) d += __shfl_xor(d, o, 64);
  if (lane == 0) out[g] = (cnt > 0) ? d / (float)cnt + cS[0] : cS[1];
}

extern "C" void kernel_launch(void* const* d_in, const int* in_sizes, int n_in,
                              void* d_out, int out_size, void* d_ws, size_t ws_size,
                              hipStream_t stream)
{
  const float* x    = (const float*)d_in[0];
  const float* act  = (const float*)d_in[1];
  const float* Wg   = (const float*)d_in[2];
  const float* bg   = (const float*)d_in[3];
  const float* g0   = (const float*)d_in[4];
  const float* be0  = (const float*)d_in[5];
  const float* W1   = (const float*)d_in[6];
  const float* b1   = (const float*)d_in[7];
  const float* g1   = (const float*)d_in[8];
  const float* be1  = (const float*)d_in[9];
  const float* W2   = (const float*)d_in[10];
  const float* b2   = (const float*)d_in[11];
  const float* g2   = (const float*)d_in[12];
  const float* be2  = (const float*)d_in[13];
  const float* W3   = (const float*)d_in[14];
  const float* b3   = (const float*)d_in[15];
  const int* eidx   = (const int*)d_in[16];
  const int* batch  = (const int*)d_in[17];

  const int N = in_sizes[17];          // 200000
  const int E = in_sizes[16] / 2;      // 1600000
  const int B = out_size;              // 1000
  const int* src = eidx;
  const int* dst = eidx + E;
  const int NB = (N + (1 << BSHIFT) - 1) >> BSHIFT;   // ~391 buckets

  char* ws = (char*)d_ws;
  size_t off = 0;
  auto alloc = [&](size_t bytes) -> char* {
    off = (off + 255) & ~(size_t)255;
    char* p = ws + off; off += bytes; return p;
  };

  u16* bufA = (u16*)alloc((size_t)N * 128 * 2);   // h0 (h1/h2 never materialized)
  u16* xb   = (u16*)alloc((size_t)N * 64 * 2);    // y (premult bf16 x)
  u16* aggx = (u16*)alloc((size_t)N * 64 * 2);

  int zwords = 768 + 128 + 2 * NB + 2 * 128 * B;  // stats+b1p+bins + P1+P2
  zwords = (zwords + 7) & ~7;                     // pad for int4-pair zeroing
  char* zbase   = alloc((size_t)zwords * 4);
  float* stats0 = (float*)zbase;
  float* stats1 = stats0 + 256;
  float* stats2 = stats1 + 256;
  float* b1p    = stats2 + 256;
  int*   btot   = (int*)(b1p + 128);
  int*   bcur   = btot + NB;
  float* P1     = (float*)(bcur + NB);            // [B,128] graph sums of h1
  float* P2     = P1 + 128 * B;                   // [B,128] graph sums of h2

  int*   offsets = (int*)alloc((size_t)(N + 1) * 4);
  float* dinv    = (float*)alloc((size_t)N * 4);
  int*   elist   = (int*)alloc((size_t)(E + N) * 4);
  uint2* pairs   = (uint2*)alloc((size_t)E * 8);
  int*   bbase   = (int*)alloc((size_t)(NB + 1) * 4);
  int*   gofs    = (int*)alloc((size_t)(B + 1) * 4);
  u16*   WghiT   = (u16*)alloc(128 * 64 * 2);
  u16*   WgloT   = (u16*)alloc(128 * 64 * 2);
  u16*   W1hiT   = (u16*)alloc(128 * 128 * 2);
  u16*   W1loT   = (u16*)alloc(128 * 128 * 2);
  u16*   W2hiT   = (u16*)alloc(128 * 32 * 2);
  u16*   W2loT   = (u16*)alloc(128 * 32 * 2);

  u16* h0 = bufA;

  // dynamic-LDS: B tiles (2*64*K u16 * 2) + sred/qred 512B + sbatch 2KB + Pacc 2KB
  const int smem64  = 2 * 64 * 64 * 2 + 512;                  // non-POOL: no window
  const int smem128 = 2 * 64 * 128 * 2 + 512 + 2048 + 2048;   // 37376 B (fused max)

  // prep0: zero scratch (parallel, ~1 MB) + weight split + graph bounds
  const int NZ = (zwords + 2047) / 2048;          // 256 thr x 8 words per block
  const int nbounds = (N + 255) / 256;
  k_prep0<<<NZ + 48 + nbounds, 256, 0, stream>>>(Wg, W2, WghiT, WgloT, W2hiT, W2loT,
                                                 batch, gofs, (int*)zbase, zwords, NZ, N, B);
  // binned edge partition -> per-bucket CSR build + fused x->y cast
  k_bincnt<<<256, 256, NB * 4, stream>>>(dst, btot, E, NB);
  k_exscan<<<1, 256, 0, stream>>>(btot, bbase, NB);
  k_bin<<<256, 256, 2 * NB * 4, stream>>>(src, dst, bbase, bcur, pairs, E, NB);
  k_bucket<<<NB, 256, 0, stream>>>(pairs, bbase, x, offsets, dinv, elist, xb, N, NB, E + N);
  // aggregate, GEMM (+stats0) -> h0
  k_agg<<<2048, 256, 0, stream>>>(xb, offsets, elist, dinv, aggx, N);
  k_gemm<64, true, true, false, false><<<768, 256, smem64, stream>>>(aggx, WghiT, WgloT, bg,
                                                                     h0, stats0, nullptr, nullptr, N);
  // fold BN0 into W1
  k_prep1<<<16, 128, 0, stream>>>(stats0, W1, b1, g0, be0, W1hiT, W1loT, b1p, (float)N);
  // FUSED: h1-GEMM (K=128, h0 -> P1) overlapped with h2-GEMM (K=32, act -> P2)
  k_gemm2<<<768 + 512, 256, smem128, stream>>>(h0, W1hiT, W1loT, b1p, stats1, P1,
                                               act, W2hiT, W2loT, b2, stats2, P2,
                                               batch, N, 768, 512);
  // merged BN1/BN2+W3 fold + per-graph head
  k_out3<<<(B * 64 + 255) / 256, 256, 0, stream>>>(P1, P2, gofs, stats1, stats2,
                                                   g1, be1, g2, be2, W3, b3,
                                                   (float*)d_out, B, (float)N);
}